// Round 3
// baseline (652.296 us; speedup 1.0000x reference)
//
#include <hip/hip_runtime.h>
#include <hip/hip_bf16.h>

// ---------------------------------------------------------------------------
// TransformerDecoderLayer on MI355X. bf16 MFMA, f32 accumulate.
// New: 8-wave 256x256xBK=64 pipelined GEMM (counted vmcnt, XOR-swizzled LDS,
// raw s_barrier, setprio) for the large GEMMs; old 128-tile kernel retained
// for N=512 shapes (sa, ffn2) where 256-tiles under-occupy.
// ---------------------------------------------------------------------------

typedef __attribute__((ext_vector_type(4))) float f32x4;
typedef __attribute__((ext_vector_type(8))) short bf16x8;

#define SCALE 0.04419417382415922f   // 1/sqrt(512)

__device__ __forceinline__ short f2bf(float f) {
  __hip_bfloat16 h = __float2bfloat16(f);
  short s; __builtin_memcpy(&s, &h, 2); return s;
}

__device__ __forceinline__ void gload16(const void* g, void* lds) {
  __builtin_amdgcn_global_load_lds(
      (const __attribute__((address_space(1))) unsigned int*)g,
      (__attribute__((address_space(3))) unsigned int*)lds, 16, 0, 0);
}

// ---------------- fused weight converts ----------------
__global__ __launch_bounds__(256) void cvt_multi(
    const float* __restrict__ s0, const float* __restrict__ s1,
    const float* __restrict__ s2, const float* __restrict__ s3,
    const float* __restrict__ s4, const float* __restrict__ s5,
    const float* __restrict__ s6,
    short* __restrict__ Wqkv, short* __restrict__ w1b, short* __restrict__ w2b,
    short* __restrict__ cwkb, short* __restrict__ cwqb) {
  int i = blockIdx.x * 256 + threadIdx.x;
  const float* src; short* dst; int k;
  if (i < 524288)       { src = s0; dst = Wqkv;           k = i; }
  else if (i < 1048576) { src = s1; dst = Wqkv + 2097152; k = i - 524288; }
  else if (i < 1572864) { src = s2; dst = Wqkv + 4194304; k = i - 1048576; }
  else if (i < 1835008) { src = s3; dst = w1b;            k = i - 1572864; }
  else if (i < 2097152) { src = s4; dst = w2b;            k = i - 1835008; }
  else if (i < 2621440) { src = s5; dst = cwkb;           k = i - 2097152; }
  else                  { src = s6; dst = cwqb;           k = i - 2621440; }
  float4 v = reinterpret_cast<const float4*>(src)[k];
  short4 o; o.x = f2bf(v.x); o.y = f2bf(v.y); o.z = f2bf(v.z); o.w = f2bf(v.w);
  reinterpret_cast<short4*>(dst)[k] = o;
}

__global__ __launch_bounds__(256) void permute_wo(const float* __restrict__ in,
                                                  short* __restrict__ out) {
  int i = blockIdx.x * 256 + threadIdx.x;
  int o = i >> 12, j = i & 4095;
  int h = j >> 9, d = j & 511;
  int h2 = d >> 6, e = d & 63;
  out[i] = f2bf(in[(o << 12) + h2 * 512 + h * 64 + e]);
}

// ---------------- block reductions ----------------
__device__ __forceinline__ float block_sum(float v, float* sm) {
  #pragma unroll
  for (int o = 1; o < 64; o <<= 1) v += __shfl_xor(v, o, 64);
  int w = threadIdx.x >> 6;
  if ((threadIdx.x & 63) == 0) sm[w] = v;
  __syncthreads();
  float r = sm[0] + sm[1] + sm[2] + sm[3];
  __syncthreads();
  return r;
}
__device__ __forceinline__ float block_max(float v, float* sm) {
  #pragma unroll
  for (int o = 1; o < 64; o <<= 1) v = fmaxf(v, __shfl_xor(v, o, 64));
  int w = threadIdx.x >> 6;
  if ((threadIdx.x & 63) == 0) sm[w] = v;
  __syncthreads();
  float r = fmaxf(fmaxf(sm[0], sm[1]), fmaxf(sm[2], sm[3]));
  __syncthreads();
  return r;
}

// ---------------- layernorm ----------------
__global__ __launch_bounds__(256) void ln_rows(const float* __restrict__ in,
    const float* __restrict__ gw, const float* __restrict__ bw,
    short* __restrict__ out, short* __restrict__ rawout) {
  __shared__ float sm[4];
  size_t row = blockIdx.x;
  const float2 v = reinterpret_cast<const float2*>(in + row * 512)[threadIdx.x];
  if (rawout) {
    short2 ro; ro.x = f2bf(v.x); ro.y = f2bf(v.y);
    reinterpret_cast<short2*>(rawout + row * 512)[threadIdx.x] = ro;
  }
  float mu = block_sum(v.x + v.y, sm) * (1.0f / 512.0f);
  float dx = v.x - mu, dy = v.y - mu;
  float var = block_sum(dx * dx + dy * dy, sm) * (1.0f / 512.0f);
  float rs = rsqrtf(var + 1e-6f);
  int c = threadIdx.x * 2;
  short2 o;
  o.x = f2bf(dx * rs * gw[c] + bw[c]);
  o.y = f2bf(dy * rs * gw[c + 1] + bw[c + 1]);
  reinterpret_cast<short2*>(out + row * 512)[threadIdx.x] = o;
}

// ---------------- softmax ----------------
template<int CAUSAL>
__global__ __launch_bounds__(256) void softmax_rows(float* __restrict__ data,
                                                    short* __restrict__ pout,
                                                    int withP) {
  __shared__ float sm[4];
  size_t row = blockIdx.x;
  const int r = (int)(row & 1023);
  float* rp = data + row * 1024;
  const int c0 = threadIdx.x * 4;
  float4 v;
  bool live = true;
  if (CAUSAL) {
    live = (c0 <= r);
    if (live) {
      v = reinterpret_cast<float4*>(rp)[threadIdx.x];
      if (c0 + 1 > r) v.y = -1.0e9f;
      if (c0 + 2 > r) v.z = -1.0e9f;
      if (c0 + 3 > r) v.w = -1.0e9f;
    } else {
      v.x = v.y = v.z = v.w = -1.0e9f;
    }
  } else {
    v = reinterpret_cast<float4*>(rp)[threadIdx.x];
  }
  float lm = live ? fmaxf(fmaxf(v.x, v.y), fmaxf(v.z, v.w)) : -1.0e30f;
  float m = block_max(lm, sm);
  float e0 = 0.f, e1 = 0.f, e2 = 0.f, e3 = 0.f;
  if (live) {
    e0 = expf(v.x - m); e1 = expf(v.y - m);
    e2 = expf(v.z - m); e3 = expf(v.w - m);
  }
  float inv = 1.0f / block_sum(e0 + e1 + e2 + e3, sm);
  float4 w; w.x = e0 * inv; w.y = e1 * inv; w.z = e2 * inv; w.w = e3 * inv;
  reinterpret_cast<float4*>(rp)[threadIdx.x] = w;
  if (withP) {
    short4 o; o.x = f2bf(w.x); o.y = f2bf(w.y); o.z = f2bf(w.z); o.w = f2bf(w.w);
    reinterpret_cast<short4*>(pout + row * 1024)[threadIdx.x] = o;
  }
}

// ===========================================================================
// 8-wave 256x256 pipelined GEMM, BK=64. Wave tile 32x256 (2 M-frags x 16
// N-frags). 4 phases per K-tile: phase=(n_half, k_sub). Stage order per
// K-tile (for t+1): A rows 0-127 (ph0), A 128-255 (ph1), B 0-127 (ph2),
// B 128-255 (ph3). Per-wave queue => vmcnt(2) gate at ph0, vmcnt(4) at ph2.
// LDS [256][8 slots of 16B] with slot ^= (row&7); global source pre-swizzled
// (rule #21: same involution both sides), gload_lds dest stays linear.
// EPI 0: QKV  1: self logits (triangular)  2: PV (K trunc)  4: ffn1-gelu
// EPI 6: cross proj (z picks A/B pair)     7: cross logits
// ===========================================================================
#define STAGE256(matbase, gbase, grow0) do {                                   \
    const int r_ = tid >> 3;                                                   \
    gload16((gbase) + (size_t)((grow0) + r_) * K + (((tid & 7) ^ (r_ & 7)) << 3), \
            (matbase) + (tid >> 6) * 512);                                     \
  } while (0)

#define BREAD(NH, KS) do {                                                     \
    _Pragma("unroll")                                                          \
    for (int nj = 0; nj < 8; ++nj) {                                           \
      const int br_ = (NH) * 128 + nj * 16 + lr;                               \
      bfr[nj] = *reinterpret_cast<const bf16x8*>(Bs_ + br_ * 64 +              \
                   (((((KS) << 2) + kh) ^ sx) << 3));                          \
    } } while (0)

#define DOMFMA(NH, KS) do {                                                    \
    __builtin_amdgcn_s_setprio(1);                                             \
    _Pragma("unroll")                                                          \
    for (int nj = 0; nj < 8; ++nj) {                                           \
      acc[0][(NH) * 8 + nj] = __builtin_amdgcn_mfma_f32_16x16x32_bf16(         \
          bfr[nj], a[0][KS], acc[0][(NH) * 8 + nj], 0, 0, 0);                  \
      acc[1][(NH) * 8 + nj] = __builtin_amdgcn_mfma_f32_16x16x32_bf16(         \
          bfr[nj], a[1][KS], acc[1][(NH) * 8 + nj], 0, 0, 0);                  \
    }                                                                          \
    __builtin_amdgcn_s_setprio(0); } while (0)

template<int EPI>
__global__ __launch_bounds__(512, 1) void gemm256(
    const short* __restrict__ A, const short* __restrict__ Bw,
    int K, long long sA, long long sB,
    const float* __restrict__ fin,
    float* __restrict__ fout, short* __restrict__ bout,
    short* __restrict__ bout2, short* __restrict__ bout3,
    const short* __restrict__ A2, const short* __restrict__ B2) {
  __shared__ short sh[65536];               // 2 buf x 2 mat x 256x64 = 128 KiB
  const int tid = threadIdx.x;
  const int wm = tid >> 6, l = tid & 63;
  const int lr = l & 15, kh = l >> 4;
  const int sx = lr & 7;
  int bx = blockIdx.x, by = blockIdx.y;
  const int z = blockIdx.z;
  if constexpr (EPI == 1) {                 // triangular: 10 tiles, bx<=by
    int idx = blockIdx.x;
    by = 0;
    while ((by + 1) * (by + 2) / 2 <= idx) ++by;
    bx = idx - by * (by + 1) / 2;
  }
  const int bm = by * 256, bn = bx * 256;
  const short* Ab; const short* Bb;
  if constexpr (EPI == 6) { Ab = z ? A2 : A; Bb = z ? B2 : Bw; }
  else { Ab = A + (size_t)z * sA; Bb = Bw + (size_t)z * sB; }

  const int kend = (EPI == 2) ? (bm + 256) : K;   // PV: P causal zeros
  const int NT = kend >> 6;

  f32x4 acc[2][16];
  #pragma unroll
  for (int mi = 0; mi < 2; ++mi)
    #pragma unroll
    for (int nj = 0; nj < 16; ++nj) acc[mi][nj] = (f32x4){0.f, 0.f, 0.f, 0.f};

  // prologue: stage tile 0 into buf 0 (canonical order A0,A1,B0,B1)
  {
    short* Asb = &sh[0];
    short* Bsb = &sh[16384];
    STAGE256(Asb,        Ab, bm);       STAGE256(Asb + 4096,  Ab, bm + 64);
    STAGE256(Asb + 8192, Ab, bm + 128); STAGE256(Asb + 12288, Ab, bm + 192);
    STAGE256(Bsb,        Bb, bn);       STAGE256(Bsb + 4096,  Bb, bn + 64);
    STAGE256(Bsb + 8192, Bb, bn + 128); STAGE256(Bsb + 12288, Bb, bn + 192);
  }

  for (int t = 0; t < NT; ++t) {
    const int cb = t & 1, nb = cb ^ 1;
    const short* As_ = &sh[cb * 32768];
    const short* Bs_ = &sh[cb * 32768 + 16384];
    short* Asn = &sh[nb * 32768];
    short* Bsn = &sh[nb * 32768 + 16384];
    const short* An = Ab + ((t + 1) << 6);
    const short* Bn = Bb + ((t + 1) << 6);
    const bool more = (t + 1 < NT);
    bf16x8 a[2][2];
    bf16x8 bfr[8];

    // ---- phase 0: gate A0,A1,B0 of tile t ----
    asm volatile("s_waitcnt vmcnt(2)" ::: "memory");
    __builtin_amdgcn_s_barrier();
    __builtin_amdgcn_sched_barrier(0);
    #pragma unroll
    for (int mi = 0; mi < 2; ++mi)
      #pragma unroll
      for (int ks = 0; ks < 2; ++ks) {
        const int ar_ = wm * 32 + mi * 16 + lr;
        a[mi][ks] = *reinterpret_cast<const bf16x8*>(As_ + ar_ * 64 +
                        ((((ks << 2) + kh) ^ sx) << 3));
      }
    BREAD(0, 0);
    if (more) { STAGE256(Asn, An, bm); STAGE256(Asn + 4096, An, bm + 64); }
    DOMFMA(0, 0);

    // ---- phase 1: no gate ----
    BREAD(0, 1);
    if (more) { STAGE256(Asn + 8192, An, bm + 128); STAGE256(Asn + 12288, An, bm + 192); }
    DOMFMA(0, 1);

    // ---- phase 2: gate B1 of tile t ----
    if (more) { asm volatile("s_waitcnt vmcnt(4)" ::: "memory"); }
    else      { asm volatile("s_waitcnt vmcnt(0)" ::: "memory"); }
    __builtin_amdgcn_s_barrier();
    __builtin_amdgcn_sched_barrier(0);
    BREAD(1, 0);
    if (more) { STAGE256(Bsn, Bn, bn); STAGE256(Bsn + 4096, Bn, bn + 64); }
    DOMFMA(1, 0);

    // ---- phase 3: no gate ----
    BREAD(1, 1);
    if (more) { STAGE256(Bsn + 8192, Bn, bn + 128); STAGE256(Bsn + 12288, Bn, bn + 192); }
    DOMFMA(1, 1);
  }

  // Epilogue. Swapped-operand C layout: lane owns row (lr field), 4 cols.
  #pragma unroll
  for (int mi = 0; mi < 2; ++mi) {
    const int grow = bm + wm * 32 + mi * 16 + lr;
    #pragma unroll
    for (int nj = 0; nj < 16; ++nj) {
      const int gcol0 = bn + nj * 16 + kh * 4;
      const float v0 = acc[mi][nj][0], v1 = acc[mi][nj][1];
      const float v2 = acc[mi][nj][2], v3 = acc[mi][nj][3];
      if constexpr (EPI == 0) {
        const int b = grow >> 10, lw = grow & 1023;
        if (bn < 4096) {
          const int h = gcol0 >> 9, o = gcol0 & 511;
          *reinterpret_cast<short4*>(&bout[(((size_t)(b * 8 + h)) * 1024 + lw) * 512 + o]) =
              make_short4(f2bf(v0), f2bf(v1), f2bf(v2), f2bf(v3));
        } else if (bn < 8192) {
          const int n2 = gcol0 - 4096, h = n2 >> 9, o = n2 & 511;
          *reinterpret_cast<short4*>(&bout2[(((size_t)(b * 8 + h)) * 1024 + lw) * 512 + o]) =
              make_short4(f2bf(v0), f2bf(v1), f2bf(v2), f2bf(v3));
        } else {
          const int n2 = gcol0 - 8192, h = n2 >> 9, o = n2 & 511;
          const size_t base = ((size_t)(b * 8 + h)) * 512;
          bout3[(base + o + 0) * 1024 + lw] = f2bf(v0);
          bout3[(base + o + 1) * 1024 + lw] = f2bf(v1);
          bout3[(base + o + 2) * 1024 + lw] = f2bf(v2);
          bout3[(base + o + 3) * 1024 + lw] = f2bf(v3);
        }
      } else if constexpr (EPI == 1) {
        float4 f;
        f.x = v0 * SCALE + (gcol0 + 0 > grow ? -1.0e9f : 0.0f);
        f.y = v1 * SCALE + (gcol0 + 1 > grow ? -1.0e9f : 0.0f);
        f.z = v2 * SCALE + (gcol0 + 2 > grow ? -1.0e9f : 0.0f);
        f.w = v3 * SCALE + (gcol0 + 3 > grow ? -1.0e9f : 0.0f);
        *reinterpret_cast<float4*>(&fout[(size_t)z * 1048576 + (size_t)grow * 1024 + gcol0]) = f;
      } else if constexpr (EPI == 2) {
        const int b = z >> 3, h = z & 7;
        *reinterpret_cast<short4*>(&bout[((size_t)(b * 1024 + grow)) * 4096 + h * 512 + gcol0]) =
            make_short4(f2bf(v0), f2bf(v1), f2bf(v2), f2bf(v3));
      } else if constexpr (EPI == 4) {
        const float4 b4 = *reinterpret_cast<const float4*>(&fin[gcol0]);
        const float x0 = v0 + b4.x, x1 = v1 + b4.y, x2 = v2 + b4.z, x3 = v3 + b4.w;
        const float g0 = 0.5f * x0 * (1.0f + erff(x0 * 0.70710678118654752f));
        const float g1 = 0.5f * x1 * (1.0f + erff(x1 * 0.70710678118654752f));
        const float g2 = 0.5f * x2 * (1.0f + erff(x2 * 0.70710678118654752f));
        const float g3 = 0.5f * x3 * (1.0f + erff(x3 * 0.70710678118654752f));
        *reinterpret_cast<short4*>(&bout[(size_t)grow * 2048 + gcol0]) =
            make_short4(f2bf(g0), f2bf(g1), f2bf(g2), f2bf(g3));
      } else if constexpr (EPI == 6) {
        const int b = grow >> 10, lw = grow & 1023;
        const int h = gcol0 >> 9, o = gcol0 & 511;
        short* bo = bout + (size_t)z * 16777216;
        *reinterpret_cast<short4*>(&bo[(((size_t)(b * 8 + h)) * 1024 + lw) * 512 + o]) =
            make_short4(f2bf(v0), f2bf(v1), f2bf(v2), f2bf(v3));
      } else if constexpr (EPI == 7) {
        float4 f; f.x = v0 * SCALE; f.y = v1 * SCALE; f.z = v2 * SCALE; f.w = v3 * SCALE;
        *reinterpret_cast<float4*>(&fout[(size_t)z * 1048576 + (size_t)grow * 1024 + gcol0]) = f;
      }
    }
  }
}

// ---------------- old 128-tile kernel (kept for N=512 shapes) ----------------
// EPI 3: sa -> fout = fin(tokens) + val   EPI 5: ffn2 -> fout/bout
template<int EPI, int BN>
__global__ __launch_bounds__(256, 2) void gemm_nt(
    const short* __restrict__ A, const short* __restrict__ Bw,
    int K, const float* __restrict__ fin, const float* __restrict__ fin2,
    float* __restrict__ fout, short* __restrict__ bout) {
  constexpr int NJ = BN / 32;
  __shared__ short As[128 * 32];
  __shared__ short Bs[BN * 32];
  const int tid = threadIdx.x;
  const int w = tid >> 6, l = tid & 63;
  const int wr = w >> 1, wc = w & 1;
  const int lr = l & 15, kh = l >> 4;
  const int bm = blockIdx.y * 128, bn = blockIdx.x * BN;
  const int ar = w * 16 + (l >> 2);
  const int ac = (l & 3) * 8;

  f32x4 acc[4][NJ];
  #pragma unroll
  for (int i = 0; i < 4; ++i)
    #pragma unroll
    for (int j = 0; j < NJ; ++j) acc[i][j] = (f32x4){0.f, 0.f, 0.f, 0.f};

  for (int k0 = 0; k0 < K; k0 += 32) {
    #pragma unroll
    for (int c = 0; c < 2; ++c)
      gload16(A + (size_t)(bm + c * 64 + ar) * K + k0 + ac, &As[c * 2048 + w * 512]);
    #pragma unroll
    for (int c = 0; c < BN / 64; ++c)
      gload16(Bw + (size_t)(bn + c * 64 + ar) * K + k0 + ac, &Bs[c * 2048 + w * 512]);
    __syncthreads();
    bf16x8 af[4], bfr[NJ];
    #pragma unroll
    for (int i = 0; i < 4; ++i)
      af[i] = *reinterpret_cast<const bf16x8*>(&As[(wr * 64 + i * 16 + lr) * 32 + kh * 8]);
    #pragma unroll
    for (int j = 0; j < NJ; ++j)
      bfr[j] = *reinterpret_cast<const bf16x8*>(&Bs[(wc * (BN / 2) + j * 16 + lr) * 32 + kh * 8]);
    #pragma unroll
    for (int i = 0; i < 4; ++i)
      #pragma unroll
      for (int j = 0; j < NJ; ++j)
        acc[i][j] = __builtin_amdgcn_mfma_f32_16x16x32_bf16(bfr[j], af[i], acc[i][j], 0, 0, 0);
    __syncthreads();
  }

  #pragma unroll
  for (int i = 0; i < 4; ++i) {
    const int grow = bm + wr * 64 + i * 16 + lr;
    #pragma unroll
    for (int j = 0; j < NJ; ++j) {
      const int gcol0 = bn + wc * (BN / 2) + j * 16 + kh * 4;
      const float v0 = acc[i][j][0], v1 = acc[i][j][1];
      const float v2 = acc[i][j][2], v3 = acc[i][j][3];
      if constexpr (EPI == 3) {
        const size_t idx = (size_t)grow * 512 + gcol0;
        const float4 t4 = *reinterpret_cast<const float4*>(&fin[idx]);
        float4 f; f.x = t4.x + v0; f.y = t4.y + v1; f.z = t4.z + v2; f.w = t4.w + v3;
        *reinterpret_cast<float4*>(&fout[idx]) = f;
      } else if constexpr (EPI == 5) {
        const size_t idx = (size_t)grow * 512 + gcol0;
        const float4 a4 = *reinterpret_cast<const float4*>(&fin2[idx]);
        const float4 b4 = *reinterpret_cast<const float4*>(&fin[gcol0]);
        float4 f;
        f.x = a4.x + v0 + b4.x; f.y = a4.y + v1 + b4.y;
        f.z = a4.z + v2 + b4.z; f.w = a4.w + v3 + b4.w;
        *reinterpret_cast<float4*>(&fout[idx]) = f;
        *reinterpret_cast<short4*>(&bout[idx]) =
            make_short4(f2bf(f.x), f2bf(f.y), f2bf(f.z), f2bf(f.w));
      }
    }
  }
}

// ---------------------------------------------------------------------------
extern "C" void kernel_launch(void* const* d_in, const int* in_sizes, int n_in,
                              void* d_out, int out_size, void* d_ws, size_t ws_size,
                              hipStream_t stream) {
  const float* tokens = (const float*)d_in[0];
  const float* ln1g = (const float*)d_in[3];
  const float* ln1b = (const float*)d_in[4];
  const float* ln2g = (const float*)d_in[5];
  const float* ln2b = (const float*)d_in[6];
  const float* wq = (const float*)d_in[7];
  const float* wk = (const float*)d_in[8];
  const float* wv = (const float*)d_in[9];
  const float* wo = (const float*)d_in[10];
  const float* w1 = (const float*)d_in[11];
  const float* b1 = (const float*)d_in[12];
  const float* w2 = (const float*)d_in[13];
  const float* b2 = (const float*)d_in[14];
  const float* cwk = (const float*)d_in[15];
  const float* cwq = (const float*)d_in[17];

  float* out_t = (float*)d_out;
  float* out_self = out_t + 2097152;
  float* out_cross = out_self + 33554432;

  char* ws = (char*)d_ws;
  size_t off = 0;
  auto alloc = [&](size_t bytes) -> void* {
    void* p = ws + off; off = (off + bytes + 255) & ~(size_t)255; return p;
  };
  short* xb   = (short*)alloc(2097152ull * 2);
  short* tokb = (short*)alloc(2097152ull * 2);
  float* tf   = (float*)alloc(2097152ull * 4);
  short* tb   = (short*)alloc(2097152ull * 2);
  short* yb   = (short*)alloc(2097152ull * 2);
  short* h1b  = (short*)alloc(8388608ull * 2);
  short* qb   = (short*)alloc(16777216ull * 2);
  short* kb   = (short*)alloc(16777216ull * 2);
  short* vtb  = (short*)alloc(16777216ull * 2);
  short* Pb   = (short*)alloc(33554432ull * 2);
  short* comb = (short*)alloc(16777216ull * 2);
  short* Wqkv = (short*)alloc(6291456ull * 2);
  short* wop  = (short*)alloc(2097152ull * 2);
  short* w1b  = (short*)alloc(1048576ull * 2);
  short* w2b  = (short*)alloc(1048576ull * 2);
  short* cwkb = (short*)alloc(2097152ull * 2);
  short* cwqb = (short*)alloc(2097152ull * 2);
  short* ckb = qb;
  short* cqb = kb;

  cvt_multi<<<12288, 256, 0, stream>>>(wq, wk, wv, w1, w2, cwk, cwq,
                                       Wqkv, w1b, w2b, cwkb, cwqb);
  permute_wo<<<8192, 256, 0, stream>>>(wo, wop);
  ln_rows<<<4096, 256, 0, stream>>>(tokens, ln1g, ln1b, xb, tokb);
  // QKV: [4096,512] x [12288,512]^T
  gemm256<0><<<dim3(48, 16, 1), 512, 0, stream>>>(xb, Wqkv, 512, 0, 0,
      nullptr, nullptr, qb, kb, vtb, nullptr, nullptr);
  // self logits: triangular 256-tiles (10) x 32 heads
  gemm256<1><<<dim3(10, 1, 32), 512, 0, stream>>>(qb, kb, 512, 524288, 524288,
      nullptr, out_self, nullptr, nullptr, nullptr, nullptr, nullptr);
  softmax_rows<1><<<32768, 256, 0, stream>>>(out_self, Pb, 1);
  // PV: K truncated per row-tile
  gemm256<2><<<dim3(2, 4, 32), 512, 0, stream>>>(Pb, vtb, 1024, 1048576, 524288,
      nullptr, nullptr, comb, nullptr, nullptr, nullptr, nullptr);
  // sa + residual (old kernel, N=512)
  gemm_nt<3, 64><<<dim3(8, 32, 1), 256, 0, stream>>>(comb, wop, 4096,
      tokens, nullptr, tf, nullptr);
  ln_rows<<<4096, 256, 0, stream>>>(tf, ln2g, ln2b, yb, nullptr);
  // ffn1 + gelu
  gemm256<4><<<dim3(8, 16, 1), 512, 0, stream>>>(yb, w1b, 512, 0, 0,
      b1, nullptr, h1b, nullptr, nullptr, nullptr, nullptr);
  // ffn2 + residuals (old kernel, N=512)
  gemm_nt<5, 64><<<dim3(8, 32, 1), 256, 0, stream>>>(h1b, w2b, 2048,
      b2, tf, out_t, tb);
  // cross projections batched: z=0 tokens*cwk -> ckb, z=1 t*cwq -> cqb
  gemm256<6><<<dim3(16, 16, 2), 512, 0, stream>>>(tokb, cwkb, 512, 0, 0,
      nullptr, nullptr, ckb, nullptr, nullptr, tb, cwqb);
  gemm256<7><<<dim3(4, 4, 32), 512, 0, stream>>>(cqb, ckb, 512, 524288, 524288,
      nullptr, out_cross, nullptr, nullptr, nullptr, nullptr, nullptr);
  softmax_rows<0><<<32768, 256, 0, stream>>>(out_cross, nullptr, 0);
}

// Round 4
// 643.516 us; speedup vs baseline: 1.0136x; 1.0136x over previous
//
#include <hip/hip_runtime.h>
#include <hip/hip_bf16.h>

// ---------------------------------------------------------------------------
// TransformerDecoderLayer on MI355X. bf16 MFMA, f32 accumulate.
// gemm256: faithful m201-style 8-phase 256x256xBK=64 pipeline — waves 2Mx4N
// (wave C = 128x64), half-tile ring stages 1.75 tiles ahead, vmcnt(6) gate
// once per K-tile, 2 barriers/phase, setprio around MFMA clusters.
// Old 128-tile kernel retained for N=512 shapes (sa, ffn2).
// ---------------------------------------------------------------------------

typedef __attribute__((ext_vector_type(4))) float f32x4;
typedef __attribute__((ext_vector_type(8))) short bf16x8;

#define SCALE 0.04419417382415922f   // 1/sqrt(512)

__device__ __forceinline__ short f2bf(float f) {
  __hip_bfloat16 h = __float2bfloat16(f);
  short s; __builtin_memcpy(&s, &h, 2); return s;
}

__device__ __forceinline__ void gload16(const void* g, void* lds) {
  __builtin_amdgcn_global_load_lds(
      (const __attribute__((address_space(1))) unsigned int*)g,
      (__attribute__((address_space(3))) unsigned int*)lds, 16, 0, 0);
}

// ---------------- fused weight converts ----------------
__global__ __launch_bounds__(256) void cvt_multi(
    const float* __restrict__ s0, const float* __restrict__ s1,
    const float* __restrict__ s2, const float* __restrict__ s3,
    const float* __restrict__ s4, const float* __restrict__ s5,
    const float* __restrict__ s6,
    short* __restrict__ Wqkv, short* __restrict__ w1b, short* __restrict__ w2b,
    short* __restrict__ cwkb, short* __restrict__ cwqb) {
  int i = blockIdx.x * 256 + threadIdx.x;
  const float* src; short* dst; int k;
  if (i < 524288)       { src = s0; dst = Wqkv;           k = i; }
  else if (i < 1048576) { src = s1; dst = Wqkv + 2097152; k = i - 524288; }
  else if (i < 1572864) { src = s2; dst = Wqkv + 4194304; k = i - 1048576; }
  else if (i < 1835008) { src = s3; dst = w1b;            k = i - 1572864; }
  else if (i < 2097152) { src = s4; dst = w2b;            k = i - 1835008; }
  else if (i < 2621440) { src = s5; dst = cwkb;           k = i - 2097152; }
  else                  { src = s6; dst = cwqb;           k = i - 2621440; }
  float4 v = reinterpret_cast<const float4*>(src)[k];
  short4 o; o.x = f2bf(v.x); o.y = f2bf(v.y); o.z = f2bf(v.z); o.w = f2bf(v.w);
  reinterpret_cast<short4*>(dst)[k] = o;
}

__global__ __launch_bounds__(256) void permute_wo(const float* __restrict__ in,
                                                  short* __restrict__ out) {
  int i = blockIdx.x * 256 + threadIdx.x;
  int o = i >> 12, j = i & 4095;
  int h = j >> 9, d = j & 511;
  int h2 = d >> 6, e = d & 63;
  out[i] = f2bf(in[(o << 12) + h2 * 512 + h * 64 + e]);
}

// ---------------- block reductions ----------------
__device__ __forceinline__ float block_sum(float v, float* sm) {
  #pragma unroll
  for (int o = 1; o < 64; o <<= 1) v += __shfl_xor(v, o, 64);
  int w = threadIdx.x >> 6;
  if ((threadIdx.x & 63) == 0) sm[w] = v;
  __syncthreads();
  float r = sm[0] + sm[1] + sm[2] + sm[3];
  __syncthreads();
  return r;
}
__device__ __forceinline__ float block_max(float v, float* sm) {
  #pragma unroll
  for (int o = 1; o < 64; o <<= 1) v = fmaxf(v, __shfl_xor(v, o, 64));
  int w = threadIdx.x >> 6;
  if ((threadIdx.x & 63) == 0) sm[w] = v;
  __syncthreads();
  float r = fmaxf(fmaxf(sm[0], sm[1]), fmaxf(sm[2], sm[3]));
  __syncthreads();
  return r;
}

// ---------------- layernorm ----------------
__global__ __launch_bounds__(256) void ln_rows(const float* __restrict__ in,
    const float* __restrict__ gw, const float* __restrict__ bw,
    short* __restrict__ out, short* __restrict__ rawout) {
  __shared__ float sm[4];
  size_t row = blockIdx.x;
  const float2 v = reinterpret_cast<const float2*>(in + row * 512)[threadIdx.x];
  if (rawout) {
    short2 ro; ro.x = f2bf(v.x); ro.y = f2bf(v.y);
    reinterpret_cast<short2*>(rawout + row * 512)[threadIdx.x] = ro;
  }
  float mu = block_sum(v.x + v.y, sm) * (1.0f / 512.0f);
  float dx = v.x - mu, dy = v.y - mu;
  float var = block_sum(dx * dx + dy * dy, sm) * (1.0f / 512.0f);
  float rs = rsqrtf(var + 1e-6f);
  int c = threadIdx.x * 2;
  short2 o;
  o.x = f2bf(dx * rs * gw[c] + bw[c]);
  o.y = f2bf(dy * rs * gw[c + 1] + bw[c + 1]);
  reinterpret_cast<short2*>(out + row * 512)[threadIdx.x] = o;
}

// ---------------- softmax ----------------
template<int CAUSAL>
__global__ __launch_bounds__(256) void softmax_rows(float* __restrict__ data,
                                                    short* __restrict__ pout,
                                                    int withP) {
  __shared__ float sm[4];
  size_t row = blockIdx.x;
  const int r = (int)(row & 1023);
  float* rp = data + row * 1024;
  const int c0 = threadIdx.x * 4;
  float4 v;
  bool live = true;
  if (CAUSAL) {
    live = (c0 <= r);
    if (live) {
      v = reinterpret_cast<float4*>(rp)[threadIdx.x];
      if (c0 + 1 > r) v.y = -1.0e9f;
      if (c0 + 2 > r) v.z = -1.0e9f;
      if (c0 + 3 > r) v.w = -1.0e9f;
    } else {
      v.x = v.y = v.z = v.w = -1.0e9f;
    }
  } else {
    v = reinterpret_cast<float4*>(rp)[threadIdx.x];
  }
  float lm = live ? fmaxf(fmaxf(v.x, v.y), fmaxf(v.z, v.w)) : -1.0e30f;
  float m = block_max(lm, sm);
  float e0 = 0.f, e1 = 0.f, e2 = 0.f, e3 = 0.f;
  if (live) {
    e0 = expf(v.x - m); e1 = expf(v.y - m);
    e2 = expf(v.z - m); e3 = expf(v.w - m);
  }
  float inv = 1.0f / block_sum(e0 + e1 + e2 + e3, sm);
  float4 w; w.x = e0 * inv; w.y = e1 * inv; w.z = e2 * inv; w.w = e3 * inv;
  reinterpret_cast<float4*>(rp)[threadIdx.x] = w;
  if (withP) {
    short4 o; o.x = f2bf(w.x); o.y = f2bf(w.y); o.z = f2bf(w.z); o.w = f2bf(w.w);
    reinterpret_cast<short4*>(pout + row * 1024)[threadIdx.x] = o;
  }
}

// ===========================================================================
// 8-phase pipelined 256x256 GEMM.
// LDS (shorts): A[buf][half] = buf*16384 + half*8192 ; B at +32768.
// Half = 128 rows x 64 cols, chunk-swizzled: LDS[r][c] = glob[r][c^(r&7)]
// (chunks of 8 bf16). Stage = 2 x global_load_lds(16B) per thread.
// Stage schedule (tile t): ph0: t+1.B1 | ph1: t+2.A0 | ph2: t+2.B0 |
// ph3: t+2.A1 ; gate vmcnt(6) fused into ph3's trailing barrier.
// EPI 0: QKV  1: self logits (triangular)  2: PV (K trunc)  4: ffn1-gelu
// EPI 6: cross proj (z picks A/B pair)     7: cross logits
// ===========================================================================
#define STAGEH(ldsoff, gbase, grow0, kcol0) do {                               \
    const int rr_ = tid >> 3;                                                  \
    const int cc_ = ((tid & 7) ^ (rr_ & 7)) << 3;                              \
    gload16((gbase) + (size_t)((grow0) + rr_) * K + (kcol0) + cc_,             \
            &sh[(ldsoff) + (tid >> 6) * 512]);                                 \
    gload16((gbase) + (size_t)((grow0) + 64 + rr_) * K + (kcol0) + cc_,        \
            &sh[(ldsoff) + 4096 + (tid >> 6) * 512]);                          \
  } while (0)

#define READ_A(g) do {                                                         \
    _Pragma("unroll")                                                          \
    for (int mi = 0; mi < 4; ++mi) {                                           \
      const int row_ = wm * 64 + mi * 16 + lr;                                 \
      _Pragma("unroll")                                                        \
      for (int ks = 0; ks < 2; ++ks)                                           \
        a[mi][ks] = *reinterpret_cast<const bf16x8*>(                          \
            &sh[abase + (g) * 8192 + row_ * 64 + ((((ks << 2) + kh) ^ sx) << 3)]); \
    } } while (0)

#define READ_B(dst, n) do {                                                    \
    _Pragma("unroll")                                                          \
    for (int njj = 0; njj < 2; ++njj) {                                        \
      const int row_ = wn * 32 + njj * 16 + lr;                                \
      _Pragma("unroll")                                                        \
      for (int ks = 0; ks < 2; ++ks)                                           \
        dst[njj][ks] = *reinterpret_cast<const bf16x8*>(                       \
            &sh[bbase + (n) * 8192 + row_ * 64 + ((((ks << 2) + kh) ^ sx) << 3)]); \
    } } while (0)

#define MFMA_PH(g, n, bb) do {                                                 \
    __builtin_amdgcn_s_setprio(1);                                             \
    _Pragma("unroll")                                                          \
    for (int mi = 0; mi < 4; ++mi)                                             \
      _Pragma("unroll")                                                        \
      for (int njj = 0; njj < 2; ++njj)                                        \
        _Pragma("unroll")                                                      \
        for (int ks = 0; ks < 2; ++ks)                                         \
          acc[(g) * 4 + mi][(n) * 2 + njj] =                                   \
              __builtin_amdgcn_mfma_f32_16x16x32_bf16(                         \
                  bb[njj][ks], a[mi][ks], acc[(g) * 4 + mi][(n) * 2 + njj],    \
                  0, 0, 0);                                                    \
    __builtin_amdgcn_s_setprio(0); } while (0)

template<int EPI>
__global__ __launch_bounds__(512, 1) void gemm256(
    const short* __restrict__ A, const short* __restrict__ Bw,
    int K, long long sA, long long sB,
    const float* __restrict__ fin,
    float* __restrict__ fout, short* __restrict__ bout,
    short* __restrict__ bout2, short* __restrict__ bout3,
    const short* __restrict__ A2, const short* __restrict__ B2) {
  __shared__ short sh[65536];               // 128 KiB
  const int tid = threadIdx.x;
  const int w = tid >> 6, l = tid & 63;
  const int wm = w >> 2, wn = w & 3;        // 2 M-waves x 4 N-waves
  const int lr = l & 15, kh = l >> 4;
  const int sx = lr & 7;
  int bx = blockIdx.x, by = blockIdx.y;
  const int z = blockIdx.z;
  if constexpr (EPI == 1) {                 // triangular: bx<=by
    int idx = blockIdx.x;
    by = 0;
    while ((by + 1) * (by + 2) / 2 <= idx) ++by;
    bx = idx - by * (by + 1) / 2;
  }
  const int bm = by * 256, bn = bx * 256;
  const short* Ab; const short* Bb;
  if constexpr (EPI == 6) { Ab = z ? A2 : A; Bb = z ? B2 : Bw; }
  else { Ab = A + (size_t)z * sA; Bb = Bw + (size_t)z * sB; }

  const int kend = (EPI == 2) ? (bm + 256) : K;
  const int NT = kend >> 6;

  f32x4 acc[8][4];
  #pragma unroll
  for (int mf = 0; mf < 8; ++mf)
    #pragma unroll
    for (int nf = 0; nf < 4; ++nf) acc[mf][nf] = (f32x4){0.f, 0.f, 0.f, 0.f};

  // prologue: tile0 all 4 halves, then tile1 {A0, B0, A1}
  STAGEH(0,     Ab, bm,       0);
  STAGEH(8192,  Ab, bm + 128, 0);
  STAGEH(32768, Bb, bn,       0);
  STAGEH(40960, Bb, bn + 128, 0);
  if (NT > 1) {
    STAGEH(16384, Ab, bm,       64);
    STAGEH(49152, Bb, bn,       64);
    STAGEH(24576, Ab, bm + 128, 64);
    asm volatile("s_waitcnt vmcnt(6)" ::: "memory");
  } else {
    asm volatile("s_waitcnt vmcnt(0)" ::: "memory");
  }
  __builtin_amdgcn_s_barrier();

  bf16x8 a[4][2], b0[2][2], b1[2][2];

  for (int t = 0; t < NT; ++t) {
    const int cb = t & 1;
    const int abase = cb * 16384;
    const int bbase = 32768 + cb * 16384;
    const int b2base = 32768 + (cb ^ 1) * 16384;
    const int kc1 = (t + 1) << 6, kc2 = (t + 2) << 6;
    const bool m1 = (t + 1 < NT), m2 = (t + 2 < NT);

    // ---- ph0: read A-g0 (8) + B-n0 (4); stage t+1.B1 ----
    READ_A(0);
    READ_B(b0, 0);
    if (m1) STAGEH(b2base + 8192, Bb, bn + 128, kc1);
    __builtin_amdgcn_s_barrier();
    asm volatile("s_waitcnt lgkmcnt(0)" ::: "memory");
    __builtin_amdgcn_sched_barrier(0);
    MFMA_PH(0, 0, b0);
    __builtin_amdgcn_s_barrier();

    // ---- ph1: read B-n1 (4); stage t+2.A0 ----
    READ_B(b1, 1);
    if (m2) STAGEH(abase, Ab, bm, kc2);
    __builtin_amdgcn_s_barrier();
    asm volatile("s_waitcnt lgkmcnt(0)" ::: "memory");
    __builtin_amdgcn_sched_barrier(0);
    MFMA_PH(0, 1, b1);
    __builtin_amdgcn_s_barrier();

    // ---- ph2: read A-g1 (8); stage t+2.B0 ----
    READ_A(1);
    if (m2) STAGEH(bbase, Bb, bn, kc2);
    __builtin_amdgcn_s_barrier();
    asm volatile("s_waitcnt lgkmcnt(0)" ::: "memory");
    __builtin_amdgcn_sched_barrier(0);
    MFMA_PH(1, 0, b0);
    __builtin_amdgcn_s_barrier();

    // ---- ph3: stage t+2.A1; MFMA g1n1; gate for t+1 ----
    if (m2) STAGEH(abase + 8192, Ab, bm + 128, kc2);
    __builtin_amdgcn_s_barrier();
    __builtin_amdgcn_sched_barrier(0);
    MFMA_PH(1, 1, b1);
    if (m1) {
      if (m2) asm volatile("s_waitcnt vmcnt(6)" ::: "memory");
      else    asm volatile("s_waitcnt vmcnt(0)" ::: "memory");
      __builtin_amdgcn_s_barrier();
    }
  }

  // Epilogue. Swapped-operand C layout: lane owns row (lr field) x 4 cols.
  #pragma unroll
  for (int mf = 0; mf < 8; ++mf) {
    const int grow = bm + (mf >> 2) * 128 + wm * 64 + (mf & 3) * 16 + lr;
    #pragma unroll
    for (int nf = 0; nf < 4; ++nf) {
      const int gcol0 = bn + (nf >> 1) * 128 + wn * 32 + (nf & 1) * 16 + kh * 4;
      const float v0 = acc[mf][nf][0], v1 = acc[mf][nf][1];
      const float v2 = acc[mf][nf][2], v3 = acc[mf][nf][3];
      if constexpr (EPI == 0) {
        const int b = grow >> 10, lw = grow & 1023;
        if (bn < 4096) {
          const int h = gcol0 >> 9, o = gcol0 & 511;
          *reinterpret_cast<short4*>(&bout[(((size_t)(b * 8 + h)) * 1024 + lw) * 512 + o]) =
              make_short4(f2bf(v0), f2bf(v1), f2bf(v2), f2bf(v3));
        } else if (bn < 8192) {
          const int n2 = gcol0 - 4096, h = n2 >> 9, o = n2 & 511;
          *reinterpret_cast<short4*>(&bout2[(((size_t)(b * 8 + h)) * 1024 + lw) * 512 + o]) =
              make_short4(f2bf(v0), f2bf(v1), f2bf(v2), f2bf(v3));
        } else {
          const int n2 = gcol0 - 8192, h = n2 >> 9, o = n2 & 511;
          const size_t base = ((size_t)(b * 8 + h)) * 512;
          bout3[(base + o + 0) * 1024 + lw] = f2bf(v0);
          bout3[(base + o + 1) * 1024 + lw] = f2bf(v1);
          bout3[(base + o + 2) * 1024 + lw] = f2bf(v2);
          bout3[(base + o + 3) * 1024 + lw] = f2bf(v3);
        }
      } else if constexpr (EPI == 1) {
        float4 f;
        f.x = v0 * SCALE + (gcol0 + 0 > grow ? -1.0e9f : 0.0f);
        f.y = v1 * SCALE + (gcol0 + 1 > grow ? -1.0e9f : 0.0f);
        f.z = v2 * SCALE + (gcol0 + 2 > grow ? -1.0e9f : 0.0f);
        f.w = v3 * SCALE + (gcol0 + 3 > grow ? -1.0e9f : 0.0f);
        *reinterpret_cast<float4*>(&fout[(size_t)z * 1048576 + (size_t)grow * 1024 + gcol0]) = f;
      } else if constexpr (EPI == 2) {
        const int b = z >> 3, h = z & 7;
        *reinterpret_cast<short4*>(&bout[((size_t)(b * 1024 + grow)) * 4096 + h * 512 + gcol0]) =
            make_short4(f2bf(v0), f2bf(v1), f2bf(v2), f2bf(v3));
      } else if constexpr (EPI == 4) {
        const float4 b4 = *reinterpret_cast<const float4*>(&fin[gcol0]);
        const float x0 = v0 + b4.x, x1 = v1 + b4.y, x2 = v2 + b4.z, x3 = v3 + b4.w;
        const float g0 = 0.5f * x0 * (1.0f + erff(x0 * 0.70710678118654752f));
        const float g1 = 0.5f * x1 * (1.0f + erff(x1 * 0.70710678118654752f));
        const float g2 = 0.5f * x2 * (1.0f + erff(x2 * 0.70710678118654752f));
        const float g3 = 0.5f * x3 * (1.0f + erff(x3 * 0.70710678118654752f));
        *reinterpret_cast<short4*>(&bout[(size_t)grow * 2048 + gcol0]) =
            make_short4(f2bf(g0), f2bf(g1), f2bf(g2), f2bf(g3));
      } else if constexpr (EPI == 6) {
        const int b = grow >> 10, lw = grow & 1023;
        const int h = gcol0 >> 9, o = gcol0 & 511;
        short* bo = bout + (size_t)z * 16777216;
        *reinterpret_cast<short4*>(&bo[(((size_t)(b * 8 + h)) * 1024 + lw) * 512 + o]) =
            make_short4(f2bf(v0), f2bf(v1), f2bf(v2), f2bf(v3));
      } else if constexpr (EPI == 7) {
        float4 f; f.x = v0 * SCALE; f.y = v1 * SCALE; f.z = v2 * SCALE; f.w = v3 * SCALE;
        *reinterpret_cast<float4*>(&fout[(size_t)z * 1048576 + (size_t)grow * 1024 + gcol0]) = f;
      }
    }
  }
}

// ---------------- old 128-tile kernel (kept for N=512 shapes) ----------------
template<int EPI, int BN>
__global__ __launch_bounds__(256, 2) void gemm_nt(
    const short* __restrict__ A, const short* __restrict__ Bw,
    int K, const float* __restrict__ fin, const float* __restrict__ fin2,
    float* __restrict__ fout, short* __restrict__ bout) {
  constexpr int NJ = BN / 32;
  __shared__ short As[128 * 32];
  __shared__ short Bs[BN * 32];
  const int tid = threadIdx.x;
  const int w = tid >> 6, l = tid & 63;
  const int wr = w >> 1, wc = w & 1;
  const int lr = l & 15, kh = l >> 4;
  const int bm = blockIdx.y * 128, bn = blockIdx.x * BN;
  const int ar = w * 16 + (l >> 2);
  const int ac = (l & 3) * 8;

  f32x4 acc[4][NJ];
  #pragma unroll
  for (int i = 0; i < 4; ++i)
    #pragma unroll
    for (int j = 0; j < NJ; ++j) acc[i][j] = (f32x4){0.f, 0.f, 0.f, 0.f};

  for (int k0 = 0; k0 < K; k0 += 32) {
    #pragma unroll
    for (int c = 0; c < 2; ++c)
      gload16(A + (size_t)(bm + c * 64 + ar) * K + k0 + ac, &As[c * 2048 + w * 512]);
    #pragma unroll
    for (int c = 0; c < BN / 64; ++c)
      gload16(Bw + (size_t)(bn + c * 64 + ar) * K + k0 + ac, &Bs[c * 2048 + w * 512]);
    __syncthreads();
    bf16x8 af[4], bfr[NJ];
    #pragma unroll
    for (int i = 0; i < 4; ++i)
      af[i] = *reinterpret_cast<const bf16x8*>(&As[(wr * 64 + i * 16 + lr) * 32 + kh * 8]);
    #pragma unroll
    for (int j = 0; j < NJ; ++j)
      bfr[j] = *reinterpret_cast<const bf16x8*>(&Bs[(wc * (BN / 2) + j * 16 + lr) * 32 + kh * 8]);
    #pragma unroll
    for (int i = 0; i < 4; ++i)
      #pragma unroll
      for (int j = 0; j < NJ; ++j)
        acc[i][j] = __builtin_amdgcn_mfma_f32_16x16x32_bf16(bfr[j], af[i], acc[i][j], 0, 0, 0);
    __syncthreads();
  }

  #pragma unroll
  for (int i = 0; i < 4; ++i) {
    const int grow = bm + wr * 64 + i * 16 + lr;
    #pragma unroll
    for (int j = 0; j < NJ; ++j) {
      const int gcol0 = bn + wc * (BN / 2) + j * 16 + kh * 4;
      const float v0 = acc[i][j][0], v1 = acc[i][j][1];
      const float v2 = acc[i][j][2], v3 = acc[i][j][3];
      if constexpr (EPI == 3) {
        const size_t idx = (size_t)grow * 512 + gcol0;
        const float4 t4 = *reinterpret_cast<const float4*>(&fin[idx]);
        float4 f; f.x = t4.x + v0; f.y = t4.y + v1; f.z = t4.z + v2; f.w = t4.w + v3;
        *reinterpret_cast<float4*>(&fout[idx]) = f;
      } else if constexpr (EPI == 5) {
        const size_t idx = (size_t)grow * 512 + gcol0;
        const float4 a4 = *reinterpret_cast<const float4*>(&fin2[idx]);
        const float4 b4 = *reinterpret_cast<const float4*>(&fin[gcol0]);
        float4 f;
        f.x = a4.x + v0 + b4.x; f.y = a4.y + v1 + b4.y;
        f.z = a4.z + v2 + b4.z; f.w = a4.w + v3 + b4.w;
        *reinterpret_cast<float4*>(&fout[idx]) = f;
        *reinterpret_cast<short4*>(&bout[idx]) =
            make_short4(f2bf(f.x), f2bf(f.y), f2bf(f.z), f2bf(f.w));
      }
    }
  }
}

// ---------------------------------------------------------------------------
extern "C" void kernel_launch(void* const* d_in, const int* in_sizes, int n_in,
                              void* d_out, int out_size, void* d_ws, size_t ws_size,
                              hipStream_t stream) {
  const float* tokens = (const float*)d_in[0];
  const float* ln1g = (const float*)d_in[3];
  const float* ln1b = (const float*)d_in[4];
  const float* ln2g = (const float*)d_in[5];
  const float* ln2b = (const float*)d_in[6];
  const float* wq = (const float*)d_in[7];
  const float* wk = (const float*)d_in[8];
  const float* wv = (const float*)d_in[9];
  const float* wo = (const float*)d_in[10];
  const float* w1 = (const float*)d_in[11];
  const float* b1 = (const float*)d_in[12];
  const float* w2 = (const float*)d_in[13];
  const float* b2 = (const float*)d_in[14];
  const float* cwk = (const float*)d_in[15];
  const float* cwq = (const float*)d_in[17];

  float* out_t = (float*)d_out;
  float* out_self = out_t + 2097152;
  float* out_cross = out_self + 33554432;

  char* ws = (char*)d_ws;
  size_t off = 0;
  auto alloc = [&](size_t bytes) -> void* {
    void* p = ws + off; off = (off + bytes + 255) & ~(size_t)255; return p;
  };
  short* xb   = (short*)alloc(2097152ull * 2);
  short* tokb = (short*)alloc(2097152ull * 2);
  float* tf   = (float*)alloc(2097152ull * 4);
  short* tb   = (short*)alloc(2097152ull * 2);
  short* yb   = (short*)alloc(2097152ull * 2);
  short* h1b  = (short*)alloc(8388608ull * 2);
  short* qb   = (short*)alloc(16777216ull * 2);
  short* kb   = (short*)alloc(16777216ull * 2);
  short* vtb  = (short*)alloc(16777216ull * 2);
  short* Pb   = (short*)alloc(33554432ull * 2);
  short* comb = (short*)alloc(16777216ull * 2);
  short* Wqkv = (short*)alloc(6291456ull * 2);
  short* wop  = (short*)alloc(2097152ull * 2);
  short* w1b  = (short*)alloc(1048576ull * 2);
  short* w2b  = (short*)alloc(1048576ull * 2);
  short* cwkb = (short*)alloc(2097152ull * 2);
  short* cwqb = (short*)alloc(2097152ull * 2);
  short* ckb = qb;
  short* cqb = kb;

  cvt_multi<<<12288, 256, 0, stream>>>(wq, wk, wv, w1, w2, cwk, cwq,
                                       Wqkv, w1b, w2b, cwkb, cwqb);
  permute_wo<<<8192, 256, 0, stream>>>(wo, wop);
  ln_rows<<<4096, 256, 0, stream>>>(tokens, ln1g, ln1b, xb, tokb);
  // QKV: [4096,512] x [12288,512]^T
  gemm256<0><<<dim3(48, 16, 1), 512, 0, stream>>>(xb, Wqkv, 512, 0, 0,
      nullptr, nullptr, qb, kb, vtb, nullptr, nullptr);
  // self logits: triangular 256-tiles (10) x 32 heads
  gemm256<1><<<dim3(10, 1, 32), 512, 0, stream>>>(qb, kb, 512, 524288, 524288,
      nullptr, out_self, nullptr, nullptr, nullptr, nullptr, nullptr);
  softmax_rows<1><<<32768, 256, 0, stream>>>(out_self, Pb, 1);
  // PV: K truncated per row-tile
  gemm256<2><<<dim3(2, 4, 32), 512, 0, stream>>>(Pb, vtb, 1024, 1048576, 524288,
      nullptr, nullptr, comb, nullptr, nullptr, nullptr, nullptr);
  // sa + residual (old kernel, N=512)
  gemm_nt<3, 64><<<dim3(8, 32, 1), 256, 0, stream>>>(comb, wop, 4096,
      tokens, nullptr, tf, nullptr);
  ln_rows<<<4096, 256, 0, stream>>>(tf, ln2g, ln2b, yb, nullptr);
  // ffn1 + gelu
  gemm256<4><<<dim3(8, 16, 1), 512, 0, stream>>>(yb, w1b, 512, 0, 0,
      b1, nullptr, h1b, nullptr, nullptr, nullptr, nullptr);
  // ffn2 + residuals (old kernel, N=512)
  gemm_nt<5, 64><<<dim3(8, 32, 1), 256, 0, stream>>>(h1b, w2b, 2048,
      b2, tf, out_t, tb);
  // cross projections batched: z=0 tokens*cwk -> ckb, z=1 t*cwq -> cqb
  gemm256<6><<<dim3(16, 16, 2), 512, 0, stream>>>(tokb, cwkb, 512, 0, 0,
      nullptr, nullptr, ckb, nullptr, nullptr, tb, cwqb);
  gemm256<7><<<dim3(4, 4, 32), 512, 0, stream>>>(cqb, ckb, 512, 524288, 524288,
      nullptr, out_cross, nullptr, nullptr, nullptr, nullptr, nullptr);
  softmax_rows<0><<<32768, 256, 0, stream>>>(out_cross, nullptr, 0);
}

// Round 5
// 621.896 us; speedup vs baseline: 1.0489x; 1.0348x over previous
//
#include <hip/hip_runtime.h>
#include <hip/hip_bf16.h>

// ---------------------------------------------------------------------------
// TransformerDecoderLayer on MI355X. bf16 MFMA, f32 accumulate.
// Softmax restructured: logits GEMMs write E = exp(logit-8) in bf16;
// rownorm kernel sums rows and writes W = E/sum (f32) to d_out; PV consumes
// raw E and scales by inv_sum in the epilogue (identical math, ~250MB less
// HBM traffic, two heavy softmax kernels removed).
// ---------------------------------------------------------------------------

typedef __attribute__((ext_vector_type(4))) float f32x4;
typedef __attribute__((ext_vector_type(8))) short bf16x8;

#define SCALE 0.04419417382415922f   // 1/sqrt(512)

__device__ __forceinline__ short f2bf(float f) {
  __hip_bfloat16 h = __float2bfloat16(f);
  short s; __builtin_memcpy(&s, &h, 2); return s;
}
__device__ __forceinline__ float bf2f(short s) {
  unsigned int u = ((unsigned int)(unsigned short)s) << 16;
  float f; __builtin_memcpy(&f, &u, 4); return f;
}

__device__ __forceinline__ void gload16(const void* g, void* lds) {
  __builtin_amdgcn_global_load_lds(
      (const __attribute__((address_space(1))) unsigned int*)g,
      (__attribute__((address_space(3))) unsigned int*)lds, 16, 0, 0);
}

// ---------------- fused weight converts ----------------
__global__ __launch_bounds__(256) void cvt_multi(
    const float* __restrict__ s0, const float* __restrict__ s1,
    const float* __restrict__ s2, const float* __restrict__ s3,
    const float* __restrict__ s4, const float* __restrict__ s5,
    const float* __restrict__ s6,
    short* __restrict__ Wqkv, short* __restrict__ w1b, short* __restrict__ w2b,
    short* __restrict__ cwkb, short* __restrict__ cwqb) {
  int i = blockIdx.x * 256 + threadIdx.x;
  const float* src; short* dst; int k;
  if (i < 524288)       { src = s0; dst = Wqkv;           k = i; }
  else if (i < 1048576) { src = s1; dst = Wqkv + 2097152; k = i - 524288; }
  else if (i < 1572864) { src = s2; dst = Wqkv + 4194304; k = i - 1048576; }
  else if (i < 1835008) { src = s3; dst = w1b;            k = i - 1572864; }
  else if (i < 2097152) { src = s4; dst = w2b;            k = i - 1835008; }
  else if (i < 2621440) { src = s5; dst = cwkb;           k = i - 2097152; }
  else                  { src = s6; dst = cwqb;           k = i - 2621440; }
  float4 v = reinterpret_cast<const float4*>(src)[k];
  short4 o; o.x = f2bf(v.x); o.y = f2bf(v.y); o.z = f2bf(v.z); o.w = f2bf(v.w);
  reinterpret_cast<short4*>(dst)[k] = o;
}

__global__ __launch_bounds__(256) void permute_wo(const float* __restrict__ in,
                                                  short* __restrict__ out) {
  int i = blockIdx.x * 256 + threadIdx.x;
  int o = i >> 12, j = i & 4095;
  int h = j >> 9, d = j & 511;
  int h2 = d >> 6, e = d & 63;
  out[i] = f2bf(in[(o << 12) + h2 * 512 + h * 64 + e]);
}

// ---------------- block reductions ----------------
__device__ __forceinline__ float block_sum(float v, float* sm) {
  #pragma unroll
  for (int o = 1; o < 64; o <<= 1) v += __shfl_xor(v, o, 64);
  int w = threadIdx.x >> 6;
  if ((threadIdx.x & 63) == 0) sm[w] = v;
  __syncthreads();
  float r = sm[0] + sm[1] + sm[2] + sm[3];
  __syncthreads();
  return r;
}

// ---------------- layernorm ----------------
__global__ __launch_bounds__(256) void ln_rows(const float* __restrict__ in,
    const float* __restrict__ gw, const float* __restrict__ bw,
    short* __restrict__ out, short* __restrict__ rawout) {
  __shared__ float sm[4];
  size_t row = blockIdx.x;
  const float2 v = reinterpret_cast<const float2*>(in + row * 512)[threadIdx.x];
  if (rawout) {
    short2 ro; ro.x = f2bf(v.x); ro.y = f2bf(v.y);
    reinterpret_cast<short2*>(rawout + row * 512)[threadIdx.x] = ro;
  }
  float mu = block_sum(v.x + v.y, sm) * (1.0f / 512.0f);
  float dx = v.x - mu, dy = v.y - mu;
  float var = block_sum(dx * dx + dy * dy, sm) * (1.0f / 512.0f);
  float rs = rsqrtf(var + 1e-6f);
  int c = threadIdx.x * 2;
  short2 o;
  o.x = f2bf(dx * rs * gw[c] + bw[c]);
  o.y = f2bf(dy * rs * gw[c + 1] + bw[c + 1]);
  reinterpret_cast<short2*>(out + row * 512)[threadIdx.x] = o;
}

// ---------------- rownorm: W = E / rowsum(E), one wave per row -------------
// CAUSAL: E cols >= live_end (= (r/256+1)*256, tile-rounded) were never
// written (ws poison) — never read them; W there = 0. In-tile masked E
// entries are exact 0, so E*inv handles them.
template<int CAUSAL>
__global__ __launch_bounds__(256) void rownorm(const short* __restrict__ E,
    float* __restrict__ W, float* __restrict__ inv_out) {
  const int wv = threadIdx.x >> 6, l = threadIdx.x & 63;
  const size_t row = (size_t)blockIdx.x * 4 + wv;
  const int r = (int)(row & 1023);
  const int live_end = CAUSAL ? (((r >> 8) + 1) << 8) : 1024;
  const short* ep = E + row * 1024;
  float s = 0.f;
  #pragma unroll
  for (int c = 0; c < 2; ++c) {
    const int c0 = c * 512 + l * 8;
    if (c0 < live_end) {
      bf16x8 v = *reinterpret_cast<const bf16x8*>(ep + c0);
      #pragma unroll
      for (int j = 0; j < 8; ++j) s += bf2f(v[j]);
    }
  }
  #pragma unroll
  for (int o = 1; o < 64; o <<= 1) s += __shfl_xor(s, o, 64);
  const float inv = 1.0f / s;
  if (CAUSAL && l == 0) inv_out[row] = inv;
  float* wp = W + row * 1024;
  #pragma unroll
  for (int c = 0; c < 4; ++c) {
    const int c0 = c * 256 + l * 4;
    float4 o4;
    if (c0 < live_end) {
      short4 v = *reinterpret_cast<const short4*>(ep + c0);
      o4.x = bf2f(v.x) * inv; o4.y = bf2f(v.y) * inv;
      o4.z = bf2f(v.z) * inv; o4.w = bf2f(v.w) * inv;
    } else { o4.x = o4.y = o4.z = o4.w = 0.f; }
    *reinterpret_cast<float4*>(wp + c0) = o4;
  }
}

// ===========================================================================
// 8-phase pipelined 256x256 GEMM (unchanged structure from round 4).
// EPI 0: QKV   1: self E=exp(logit-8) bf16 (triangular)  2: PV x inv_sum
// EPI 4: ffn1-gelu   6: cross proj (z picks pair)   7: cross E bf16
// ===========================================================================
#define STAGEH(ldsoff, gbase, grow0, kcol0) do {                               \
    const int rr_ = tid >> 3;                                                  \
    const int cc_ = ((tid & 7) ^ (rr_ & 7)) << 3;                              \
    gload16((gbase) + (size_t)((grow0) + rr_) * K + (kcol0) + cc_,             \
            &sh[(ldsoff) + (tid >> 6) * 512]);                                 \
    gload16((gbase) + (size_t)((grow0) + 64 + rr_) * K + (kcol0) + cc_,        \
            &sh[(ldsoff) + 4096 + (tid >> 6) * 512]);                          \
  } while (0)

#define READ_A(g) do {                                                         \
    _Pragma("unroll")                                                          \
    for (int mi = 0; mi < 4; ++mi) {                                           \
      const int row_ = wm * 64 + mi * 16 + lr;                                 \
      _Pragma("unroll")                                                        \
      for (int ks = 0; ks < 2; ++ks)                                           \
        a[mi][ks] = *reinterpret_cast<const bf16x8*>(                          \
            &sh[abase + (g) * 8192 + row_ * 64 + ((((ks << 2) + kh) ^ sx) << 3)]); \
    } } while (0)

#define READ_B(dst, n) do {                                                    \
    _Pragma("unroll")                                                          \
    for (int njj = 0; njj < 2; ++njj) {                                        \
      const int row_ = wn * 32 + njj * 16 + lr;                                \
      _Pragma("unroll")                                                        \
      for (int ks = 0; ks < 2; ++ks)                                           \
        dst[njj][ks] = *reinterpret_cast<const bf16x8*>(                       \
            &sh[bbase + (n) * 8192 + row_ * 64 + ((((ks << 2) + kh) ^ sx) << 3)]); \
    } } while (0)

#define MFMA_PH(g, n, bb) do {                                                 \
    __builtin_amdgcn_s_setprio(1);                                             \
    _Pragma("unroll")                                                          \
    for (int mi = 0; mi < 4; ++mi)                                             \
      _Pragma("unroll")                                                        \
      for (int njj = 0; njj < 2; ++njj)                                        \
        _Pragma("unroll")                                                      \
        for (int ks = 0; ks < 2; ++ks)                                         \
          acc[(g) * 4 + mi][(n) * 2 + njj] =                                   \
              __builtin_amdgcn_mfma_f32_16x16x32_bf16(                         \
                  bb[njj][ks], a[mi][ks], acc[(g) * 4 + mi][(n) * 2 + njj],    \
                  0, 0, 0);                                                    \
    __builtin_amdgcn_s_setprio(0); } while (0)

template<int EPI>
__global__ __launch_bounds__(512, 1) void gemm256(
    const short* __restrict__ A, const short* __restrict__ Bw,
    int K, long long sA, long long sB,
    const float* __restrict__ fin,
    float* __restrict__ fout, short* __restrict__ bout,
    short* __restrict__ bout2, short* __restrict__ bout3,
    const short* __restrict__ A2, const short* __restrict__ B2) {
  __shared__ short sh[65536];               // 128 KiB
  const int tid = threadIdx.x;
  const int w = tid >> 6, l = tid & 63;
  const int wm = w >> 2, wn = w & 3;        // 2 M-waves x 4 N-waves
  const int lr = l & 15, kh = l >> 4;
  const int sx = lr & 7;
  int bx = blockIdx.x, by = blockIdx.y;
  const int z = blockIdx.z;
  if constexpr (EPI == 1) {                 // triangular: bx<=by
    int idx = blockIdx.x;
    by = 0;
    while ((by + 1) * (by + 2) / 2 <= idx) ++by;
    bx = idx - by * (by + 1) / 2;
  }
  const int bm = by * 256, bn = bx * 256;
  const short* Ab; const short* Bb;
  if constexpr (EPI == 6) { Ab = z ? A2 : A; Bb = z ? B2 : Bw; }
  else { Ab = A + (size_t)z * sA; Bb = Bw + (size_t)z * sB; }

  const int kend = (EPI == 2) ? (bm + 256) : K;
  const int NT = kend >> 6;

  f32x4 acc[8][4];
  #pragma unroll
  for (int mf = 0; mf < 8; ++mf)
    #pragma unroll
    for (int nf = 0; nf < 4; ++nf) acc[mf][nf] = (f32x4){0.f, 0.f, 0.f, 0.f};

  // prologue: tile0 all 4 halves, then tile1 {A0, B0, A1}
  STAGEH(0,     Ab, bm,       0);
  STAGEH(8192,  Ab, bm + 128, 0);
  STAGEH(32768, Bb, bn,       0);
  STAGEH(40960, Bb, bn + 128, 0);
  if (NT > 1) {
    STAGEH(16384, Ab, bm,       64);
    STAGEH(49152, Bb, bn,       64);
    STAGEH(24576, Ab, bm + 128, 64);
    asm volatile("s_waitcnt vmcnt(6)" ::: "memory");
  } else {
    asm volatile("s_waitcnt vmcnt(0)" ::: "memory");
  }
  __builtin_amdgcn_s_barrier();

  bf16x8 a[4][2], b0[2][2], b1[2][2];

  for (int t = 0; t < NT; ++t) {
    const int cb = t & 1;
    const int abase = cb * 16384;
    const int bbase = 32768 + cb * 16384;
    const int b2base = 32768 + (cb ^ 1) * 16384;
    const int kc1 = (t + 1) << 6, kc2 = (t + 2) << 6;
    const bool m1 = (t + 1 < NT), m2 = (t + 2 < NT);

    // ---- ph0: read A-g0 + B-n0; stage t+1.B1 ----
    READ_A(0);
    READ_B(b0, 0);
    if (m1) STAGEH(b2base + 8192, Bb, bn + 128, kc1);
    __builtin_amdgcn_s_barrier();
    asm volatile("s_waitcnt lgkmcnt(0)" ::: "memory");
    __builtin_amdgcn_sched_barrier(0);
    MFMA_PH(0, 0, b0);
    __builtin_amdgcn_s_barrier();

    // ---- ph1: read B-n1; stage t+2.A0 ----
    READ_B(b1, 1);
    if (m2) STAGEH(abase, Ab, bm, kc2);
    __builtin_amdgcn_s_barrier();
    asm volatile("s_waitcnt lgkmcnt(0)" ::: "memory");
    __builtin_amdgcn_sched_barrier(0);
    MFMA_PH(0, 1, b1);
    __builtin_amdgcn_s_barrier();

    // ---- ph2: read A-g1; stage t+2.B0 ----
    READ_A(1);
    if (m2) STAGEH(bbase, Bb, bn, kc2);
    __builtin_amdgcn_s_barrier();
    asm volatile("s_waitcnt lgkmcnt(0)" ::: "memory");
    __builtin_amdgcn_sched_barrier(0);
    MFMA_PH(1, 0, b0);
    __builtin_amdgcn_s_barrier();

    // ---- ph3: stage t+2.A1; MFMA g1n1; gate for t+1 ----
    if (m2) STAGEH(abase + 8192, Ab, bm + 128, kc2);
    __builtin_amdgcn_s_barrier();
    __builtin_amdgcn_sched_barrier(0);
    MFMA_PH(1, 1, b1);
    if (m1) {
      if (m2) asm volatile("s_waitcnt vmcnt(6)" ::: "memory");
      else    asm volatile("s_waitcnt vmcnt(0)" ::: "memory");
      __builtin_amdgcn_s_barrier();
    }
  }

  // Epilogue. Swapped-operand C layout: lane owns row (lr field) x 4 cols.
  #pragma unroll
  for (int mf = 0; mf < 8; ++mf) {
    const int grow = bm + (mf >> 2) * 128 + wm * 64 + (mf & 3) * 16 + lr;
    #pragma unroll
    for (int nf = 0; nf < 4; ++nf) {
      const int gcol0 = bn + (nf >> 1) * 128 + wn * 32 + (nf & 1) * 16 + kh * 4;
      const float v0 = acc[mf][nf][0], v1 = acc[mf][nf][1];
      const float v2 = acc[mf][nf][2], v3 = acc[mf][nf][3];
      if constexpr (EPI == 0) {
        const int b = grow >> 10, lw = grow & 1023;
        if (bn < 4096) {
          const int h = gcol0 >> 9, o = gcol0 & 511;
          *reinterpret_cast<short4*>(&bout[(((size_t)(b * 8 + h)) * 1024 + lw) * 512 + o]) =
              make_short4(f2bf(v0), f2bf(v1), f2bf(v2), f2bf(v3));
        } else if (bn < 8192) {
          const int n2 = gcol0 - 4096, h = n2 >> 9, o = n2 & 511;
          *reinterpret_cast<short4*>(&bout2[(((size_t)(b * 8 + h)) * 1024 + lw) * 512 + o]) =
              make_short4(f2bf(v0), f2bf(v1), f2bf(v2), f2bf(v3));
        } else {
          const int n2 = gcol0 - 8192, h = n2 >> 9, o = n2 & 511;
          const size_t base = ((size_t)(b * 8 + h)) * 512;
          bout3[(base + o + 0) * 1024 + lw] = f2bf(v0);
          bout3[(base + o + 1) * 1024 + lw] = f2bf(v1);
          bout3[(base + o + 2) * 1024 + lw] = f2bf(v2);
          bout3[(base + o + 3) * 1024 + lw] = f2bf(v3);
        }
      } else if constexpr (EPI == 1) {
        // E = exp(logit - 8) bf16, masked -> exact 0
        short4 o;
        o.x = (gcol0 + 0 > grow) ? (short)0 : f2bf(__expf(v0 * SCALE - 8.0f));
        o.y = (gcol0 + 1 > grow) ? (short)0 : f2bf(__expf(v1 * SCALE - 8.0f));
        o.z = (gcol0 + 2 > grow) ? (short)0 : f2bf(__expf(v2 * SCALE - 8.0f));
        o.w = (gcol0 + 3 > grow) ? (short)0 : f2bf(__expf(v3 * SCALE - 8.0f));
        *reinterpret_cast<short4*>(&bout[(size_t)z * 1048576 + (size_t)grow * 1024 + gcol0]) = o;
      } else if constexpr (EPI == 2) {
        const float inv = fin[(size_t)z * 1024 + grow];
        const int b = z >> 3, h = z & 7;
        *reinterpret_cast<short4*>(&bout[((size_t)(b * 1024 + grow)) * 4096 + h * 512 + gcol0]) =
            make_short4(f2bf(v0 * inv), f2bf(v1 * inv), f2bf(v2 * inv), f2bf(v3 * inv));
      } else if constexpr (EPI == 4) {
        const float4 b4 = *reinterpret_cast<const float4*>(&fin[gcol0]);
        const float x0 = v0 + b4.x, x1 = v1 + b4.y, x2 = v2 + b4.z, x3 = v3 + b4.w;
        const float g0 = 0.5f * x0 * (1.0f + erff(x0 * 0.70710678118654752f));
        const float g1 = 0.5f * x1 * (1.0f + erff(x1 * 0.70710678118654752f));
        const float g2 = 0.5f * x2 * (1.0f + erff(x2 * 0.70710678118654752f));
        const float g3 = 0.5f * x3 * (1.0f + erff(x3 * 0.70710678118654752f));
        *reinterpret_cast<short4*>(&bout[(size_t)grow * 2048 + gcol0]) =
            make_short4(f2bf(g0), f2bf(g1), f2bf(g2), f2bf(g3));
      } else if constexpr (EPI == 6) {
        const int b = grow >> 10, lw = grow & 1023;
        const int h = gcol0 >> 9, o = gcol0 & 511;
        short* bo = bout + (size_t)z * 16777216;
        *reinterpret_cast<short4*>(&bo[(((size_t)(b * 8 + h)) * 1024 + lw) * 512 + o]) =
            make_short4(f2bf(v0), f2bf(v1), f2bf(v2), f2bf(v3));
      } else if constexpr (EPI == 7) {
        short4 o;
        o.x = f2bf(__expf(v0 * SCALE - 8.0f));
        o.y = f2bf(__expf(v1 * SCALE - 8.0f));
        o.z = f2bf(__expf(v2 * SCALE - 8.0f));
        o.w = f2bf(__expf(v3 * SCALE - 8.0f));
        *reinterpret_cast<short4*>(&bout[(size_t)z * 1048576 + (size_t)grow * 1024 + gcol0]) = o;
      }
    }
  }
}

// ---------------- old 128-tile kernel (kept for N=512 shapes) ----------------
template<int EPI, int BN>
__global__ __launch_bounds__(256, 2) void gemm_nt(
    const short* __restrict__ A, const short* __restrict__ Bw,
    int K, const float* __restrict__ fin, const float* __restrict__ fin2,
    float* __restrict__ fout, short* __restrict__ bout) {
  constexpr int NJ = BN / 32;
  __shared__ short As[128 * 32];
  __shared__ short Bs[BN * 32];
  const int tid = threadIdx.x;
  const int w = tid >> 6, l = tid & 63;
  const int wr = w >> 1, wc = w & 1;
  const int lr = l & 15, kh = l >> 4;
  const int bm = blockIdx.y * 128, bn = blockIdx.x * BN;
  const int ar = w * 16 + (l >> 2);
  const int ac = (l & 3) * 8;

  f32x4 acc[4][NJ];
  #pragma unroll
  for (int i = 0; i < 4; ++i)
    #pragma unroll
    for (int j = 0; j < NJ; ++j) acc[i][j] = (f32x4){0.f, 0.f, 0.f, 0.f};

  for (int k0 = 0; k0 < K; k0 += 32) {
    #pragma unroll
    for (int c = 0; c < 2; ++c)
      gload16(A + (size_t)(bm + c * 64 + ar) * K + k0 + ac, &As[c * 2048 + w * 512]);
    #pragma unroll
    for (int c = 0; c < BN / 64; ++c)
      gload16(Bw + (size_t)(bn + c * 64 + ar) * K + k0 + ac, &Bs[c * 2048 + w * 512]);
    __syncthreads();
    bf16x8 af[4], bfr[NJ];
    #pragma unroll
    for (int i = 0; i < 4; ++i)
      af[i] = *reinterpret_cast<const bf16x8*>(&As[(wr * 64 + i * 16 + lr) * 32 + kh * 8]);
    #pragma unroll
    for (int j = 0; j < NJ; ++j)
      bfr[j] = *reinterpret_cast<const bf16x8*>(&Bs[(wc * (BN / 2) + j * 16 + lr) * 32 + kh * 8]);
    #pragma unroll
    for (int i = 0; i < 4; ++i)
      #pragma unroll
      for (int j = 0; j < NJ; ++j)
        acc[i][j] = __builtin_amdgcn_mfma_f32_16x16x32_bf16(bfr[j], af[i], acc[i][j], 0, 0, 0);
    __syncthreads();
  }

  #pragma unroll
  for (int i = 0; i < 4; ++i) {
    const int grow = bm + wr * 64 + i * 16 + lr;
    #pragma unroll
    for (int j = 0; j < NJ; ++j) {
      const int gcol0 = bn + wc * (BN / 2) + j * 16 + kh * 4;
      const float v0 = acc[i][j][0], v1 = acc[i][j][1];
      const float v2 = acc[i][j][2], v3 = acc[i][j][3];
      if constexpr (EPI == 3) {
        const size_t idx = (size_t)grow * 512 + gcol0;
        const float4 t4 = *reinterpret_cast<const float4*>(&fin[idx]);
        float4 f; f.x = t4.x + v0; f.y = t4.y + v1; f.z = t4.z + v2; f.w = t4.w + v3;
        *reinterpret_cast<float4*>(&fout[idx]) = f;
      } else if constexpr (EPI == 5) {
        const size_t idx = (size_t)grow * 512 + gcol0;
        const float4 a4 = *reinterpret_cast<const float4*>(&fin2[idx]);
        const float4 b4 = *reinterpret_cast<const float4*>(&fin[gcol0]);
        float4 f;
        f.x = a4.x + v0 + b4.x; f.y = a4.y + v1 + b4.y;
        f.z = a4.z + v2 + b4.z; f.w = a4.w + v3 + b4.w;
        *reinterpret_cast<float4*>(&fout[idx]) = f;
        *reinterpret_cast<short4*>(&bout[idx]) =
            make_short4(f2bf(f.x), f2bf(f.y), f2bf(f.z), f2bf(f.w));
      }
    }
  }
}

// ---------------------------------------------------------------------------
extern "C" void kernel_launch(void* const* d_in, const int* in_sizes, int n_in,
                              void* d_out, int out_size, void* d_ws, size_t ws_size,
                              hipStream_t stream) {
  const float* tokens = (const float*)d_in[0];
  const float* ln1g = (const float*)d_in[3];
  const float* ln1b = (const float*)d_in[4];
  const float* ln2g = (const float*)d_in[5];
  const float* ln2b = (const float*)d_in[6];
  const float* wq = (const float*)d_in[7];
  const float* wk = (const float*)d_in[8];
  const float* wv = (const float*)d_in[9];
  const float* wo = (const float*)d_in[10];
  const float* w1 = (const float*)d_in[11];
  const float* b1 = (const float*)d_in[12];
  const float* w2 = (const float*)d_in[13];
  const float* b2 = (const float*)d_in[14];
  const float* cwk = (const float*)d_in[15];
  const float* cwq = (const float*)d_in[17];

  float* out_t = (float*)d_out;
  float* out_self = out_t + 2097152;
  float* out_cross = out_self + 33554432;

  char* ws = (char*)d_ws;
  size_t off = 0;
  auto alloc = [&](size_t bytes) -> void* {
    void* p = ws + off; off = (off + bytes + 255) & ~(size_t)255; return p;
  };
  short* xb   = (short*)alloc(2097152ull * 2);
  short* tokb = (short*)alloc(2097152ull * 2);
  float* tf   = (float*)alloc(2097152ull * 4);
  short* tb   = (short*)alloc(2097152ull * 2);
  short* yb   = (short*)alloc(2097152ull * 2);
  short* h1b  = (short*)alloc(8388608ull * 2);
  short* qb   = (short*)alloc(16777216ull * 2);
  short* kb   = (short*)alloc(16777216ull * 2);
  short* vtb  = (short*)alloc(16777216ull * 2);
  short* Eb   = (short*)alloc(33554432ull * 2);  // exp(logit-8) bf16
  short* comb = (short*)alloc(16777216ull * 2);
  short* Wqkv = (short*)alloc(6291456ull * 2);
  short* wop  = (short*)alloc(2097152ull * 2);
  short* w1b  = (short*)alloc(1048576ull * 2);
  short* w2b  = (short*)alloc(1048576ull * 2);
  short* cwkb = (short*)alloc(2097152ull * 2);
  short* cwqb = (short*)alloc(2097152ull * 2);
  float* inv_s = (float*)alloc(32768ull * 4);    // 1/rowsum for self attn
  short* ckb = qb;
  short* cqb = kb;

  cvt_multi<<<12288, 256, 0, stream>>>(wq, wk, wv, w1, w2, cwk, cwq,
                                       Wqkv, w1b, w2b, cwkb, cwqb);
  permute_wo<<<8192, 256, 0, stream>>>(wo, wop);
  ln_rows<<<4096, 256, 0, stream>>>(tokens, ln1g, ln1b, xb, tokb);
  // QKV: [4096,512] x [12288,512]^T
  gemm256<0><<<dim3(48, 16, 1), 512, 0, stream>>>(xb, Wqkv, 512, 0, 0,
      nullptr, nullptr, qb, kb, vtb, nullptr, nullptr);
  // self E = exp(logits-8) bf16: triangular 256-tiles (10) x 32 heads
  gemm256<1><<<dim3(10, 1, 32), 512, 0, stream>>>(qb, kb, 512, 524288, 524288,
      nullptr, nullptr, Eb, nullptr, nullptr, nullptr, nullptr);
  // W = E/sum -> d_out (dense), store inv sums
  rownorm<1><<<8192, 256, 0, stream>>>(Eb, out_self, inv_s);
  // PV on raw E, scale by inv in epilogue; K truncated per row-tile
  gemm256<2><<<dim3(2, 4, 32), 512, 0, stream>>>(Eb, vtb, 1024, 1048576, 524288,
      inv_s, nullptr, comb, nullptr, nullptr, nullptr, nullptr);
  // sa + residual (old kernel, N=512)
  gemm_nt<3, 64><<<dim3(8, 32, 1), 256, 0, stream>>>(comb, wop, 4096,
      tokens, nullptr, tf, nullptr);
  ln_rows<<<4096, 256, 0, stream>>>(tf, ln2g, ln2b, yb, nullptr);
  // ffn1 + gelu
  gemm256<4><<<dim3(8, 16, 1), 512, 0, stream>>>(yb, w1b, 512, 0, 0,
      b1, nullptr, h1b, nullptr, nullptr, nullptr, nullptr);
  // ffn2 + residuals (old kernel, N=512)
  gemm_nt<5, 64><<<dim3(8, 32, 1), 256, 0, stream>>>(h1b, w2b, 2048,
      b2, tf, out_t, tb);
  // cross projections batched: z=0 tokens*cwk -> ckb, z=1 t*cwq -> cqb
  gemm256<6><<<dim3(16, 16, 2), 512, 0, stream>>>(tokb, cwkb, 512, 0, 0,
      nullptr, nullptr, ckb, nullptr, nullptr, tb, cwqb);
  // cross E = exp(logits-8) bf16 (full grid)
  gemm256<7><<<dim3(4, 4, 32), 512, 0, stream>>>(cqb, ckb, 512, 524288, 524288,
      nullptr, nullptr, Eb, nullptr, nullptr, nullptr, nullptr);
  // cross W = E/sum -> d_out
  rownorm<0><<<8192, 256, 0, stream>>>(Eb, out_cross, nullptr);
}

// Round 6
// 561.037 us; speedup vs baseline: 1.1627x; 1.1085x over previous
//
#include <hip/hip_runtime.h>
#include <hip/hip_bf16.h>

// ---------------------------------------------------------------------------
// TransformerDecoderLayer on MI355X. bf16 MFMA, f32 accumulate.
// Algebraic restructure: logits = x*(wq^T wk)*x^T — k/ck/cq projections are
// never computed. N_h = wq_h^T wk_h and M_h = cwq_h^T cwk_h built by a tiny
// batched GEMM from transposed weights; self logits = qn*x^T, cross logits =
// (t*M)*tokens^T. E = exp(logit-8) bf16 scheme from round 5 retained.
// ---------------------------------------------------------------------------

typedef __attribute__((ext_vector_type(4))) float f32x4;
typedef __attribute__((ext_vector_type(8))) short bf16x8;

#define SCALE 0.04419417382415922f   // 1/sqrt(512)

__device__ __forceinline__ short f2bf(float f) {
  __hip_bfloat16 h = __float2bfloat16(f);
  short s; __builtin_memcpy(&s, &h, 2); return s;
}
__device__ __forceinline__ float bf2f(short s) {
  unsigned int u = ((unsigned int)(unsigned short)s) << 16;
  float f; __builtin_memcpy(&f, &u, 4); return f;
}

__device__ __forceinline__ void gload16(const void* g, void* lds) {
  __builtin_amdgcn_global_load_lds(
      (const __attribute__((address_space(1))) unsigned int*)g,
      (__attribute__((address_space(3))) unsigned int*)lds, 16, 0, 0);
}

// ---------------- weight transpose + bf16: T[h][d][o] = W[h][o][d] ----------
// z encodes tensor (z>>3: 0=wq 1=wk 2=cwq 3=cwk) and head (z&7).
__global__ __launch_bounds__(256) void transpose_w(
    const float* __restrict__ wq, const float* __restrict__ wk,
    const float* __restrict__ cwq, const float* __restrict__ cwk,
    short* __restrict__ wqT, short* __restrict__ wkT,
    short* __restrict__ cwqT, short* __restrict__ cwkT) {
  __shared__ float tile[32][33];
  const int t = blockIdx.z >> 3, h = blockIdx.z & 7;
  const float* in = (t == 0) ? wq : (t == 1) ? wk : (t == 2) ? cwq : cwk;
  short* out = (t == 0) ? wqT : (t == 1) ? wkT : (t == 2) ? cwqT : cwkT;
  const int tx = threadIdx.x & 31, ty = threadIdx.x >> 5;
  const size_t base = (size_t)h * 262144;
  #pragma unroll
  for (int r = 0; r < 4; ++r) {
    const int o = blockIdx.y * 32 + ty + r * 8;
    tile[ty + r * 8][tx] = in[base + (size_t)o * 512 + blockIdx.x * 32 + tx];
  }
  __syncthreads();
  #pragma unroll
  for (int r = 0; r < 4; ++r) {
    const int d = blockIdx.x * 32 + ty + r * 8;
    out[base + (size_t)d * 512 + blockIdx.y * 32 + tx] = f2bf(tile[tx][ty + r * 8]);
  }
}

// ---------------- fused weight converts: wv -> Wstack[4096:], w1, w2 -------
__global__ __launch_bounds__(256) void cvt_multi(
    const float* __restrict__ s0, const float* __restrict__ s1,
    const float* __restrict__ s2,
    short* __restrict__ Wv, short* __restrict__ w1b, short* __restrict__ w2b) {
  int i = blockIdx.x * 256 + threadIdx.x;   // 1,048,576 float4 jobs
  const float* src; short* dst; int k;
  if (i < 524288)      { src = s0; dst = Wv;  k = i; }
  else if (i < 786432) { src = s1; dst = w1b; k = i - 524288; }
  else                 { src = s2; dst = w2b; k = i - 786432; }
  float4 v = reinterpret_cast<const float4*>(src)[k];
  short4 o; o.x = f2bf(v.x); o.y = f2bf(v.y); o.z = f2bf(v.z); o.w = f2bf(v.w);
  reinterpret_cast<short4*>(dst)[k] = o;
}

__global__ __launch_bounds__(256) void permute_wo(const float* __restrict__ in,
                                                  short* __restrict__ out) {
  int i = blockIdx.x * 256 + threadIdx.x;
  int o = i >> 12, j = i & 4095;
  int h = j >> 9, d = j & 511;
  int h2 = d >> 6, e = d & 63;
  out[i] = f2bf(in[(o << 12) + h2 * 512 + h * 64 + e]);
}

// ---------------- block reductions ----------------
__device__ __forceinline__ float block_sum(float v, float* sm) {
  #pragma unroll
  for (int o = 1; o < 64; o <<= 1) v += __shfl_xor(v, o, 64);
  int w = threadIdx.x >> 6;
  if ((threadIdx.x & 63) == 0) sm[w] = v;
  __syncthreads();
  float r = sm[0] + sm[1] + sm[2] + sm[3];
  __syncthreads();
  return r;
}

// ---------------- layernorm ----------------
__global__ __launch_bounds__(256) void ln_rows(const float* __restrict__ in,
    const float* __restrict__ gw, const float* __restrict__ bw,
    short* __restrict__ out, short* __restrict__ rawout) {
  __shared__ float sm[4];
  size_t row = blockIdx.x;
  const float2 v = reinterpret_cast<const float2*>(in + row * 512)[threadIdx.x];
  if (rawout) {
    short2 ro; ro.x = f2bf(v.x); ro.y = f2bf(v.y);
    reinterpret_cast<short2*>(rawout + row * 512)[threadIdx.x] = ro;
  }
  float mu = block_sum(v.x + v.y, sm) * (1.0f / 512.0f);
  float dx = v.x - mu, dy = v.y - mu;
  float var = block_sum(dx * dx + dy * dy, sm) * (1.0f / 512.0f);
  float rs = rsqrtf(var + 1e-6f);
  int c = threadIdx.x * 2;
  short2 o;
  o.x = f2bf(dx * rs * gw[c] + bw[c]);
  o.y = f2bf(dy * rs * gw[c + 1] + bw[c + 1]);
  reinterpret_cast<short2*>(out + row * 512)[threadIdx.x] = o;
}

// ---------------- rownorm: W = E / rowsum(E), one wave per row -------------
template<int CAUSAL>
__global__ __launch_bounds__(256) void rownorm(const short* __restrict__ E,
    float* __restrict__ W, float* __restrict__ inv_out) {
  const int wv = threadIdx.x >> 6, l = threadIdx.x & 63;
  const size_t row = (size_t)blockIdx.x * 4 + wv;
  const int r = (int)(row & 1023);
  const int live_end = CAUSAL ? (((r >> 8) + 1) << 8) : 1024;
  const short* ep = E + row * 1024;
  float s = 0.f;
  #pragma unroll
  for (int c = 0; c < 2; ++c) {
    const int c0 = c * 512 + l * 8;
    if (c0 < live_end) {
      bf16x8 v = *reinterpret_cast<const bf16x8*>(ep + c0);
      #pragma unroll
      for (int j = 0; j < 8; ++j) s += bf2f(v[j]);
    }
  }
  #pragma unroll
  for (int o = 1; o < 64; o <<= 1) s += __shfl_xor(s, o, 64);
  const float inv = 1.0f / s;
  if (CAUSAL && l == 0) inv_out[row] = inv;
  float* wp = W + row * 1024;
  #pragma unroll
  for (int c = 0; c < 4; ++c) {
    const int c0 = c * 256 + l * 4;
    float4 o4;
    if (c0 < live_end) {
      short4 v = *reinterpret_cast<const short4*>(ep + c0);
      o4.x = bf2f(v.x) * inv; o4.y = bf2f(v.y) * inv;
      o4.z = bf2f(v.z) * inv; o4.w = bf2f(v.w) * inv;
    } else { o4.x = o4.y = o4.z = o4.w = 0.f; }
    *reinterpret_cast<float4*>(wp + c0) = o4;
  }
}

// ===========================================================================
// 8-phase pipelined 256x256 GEMM.
// EPI 0: x*[NhT;wv] -> qn [B,H,L,D], v^T [B,H,D,L]
// EPI 1: self E=exp(qn.x^T*SCALE-8) bf16, triangular; B per-batch stride
// EPI 2: PV x inv_sum -> comb
// EPI 6: tM = t*MhT (z=0 only)
// EPI 7: cross E bf16; B (=tokens) per-batch stride
// EPI 8: N_h/M_h producer: z<8 (wqT,wkT)->NhT in bout; z>=8 (cwqT,cwkT)->bout2
// ===========================================================================
#define STAGEH(ldsoff, gbase, grow0, kcol0) do {                               \
    const int rr_ = tid >> 3;                                                  \
    const int cc_ = ((tid & 7) ^ (rr_ & 7)) << 3;                              \
    gload16((gbase) + (size_t)((grow0) + rr_) * K + (kcol0) + cc_,             \
            &sh[(ldsoff) + (tid >> 6) * 512]);                                 \
    gload16((gbase) + (size_t)((grow0) + 64 + rr_) * K + (kcol0) + cc_,        \
            &sh[(ldsoff) + 4096 + (tid >> 6) * 512]);                          \
  } while (0)

#define READ_A(g) do {                                                         \
    _Pragma("unroll")                                                          \
    for (int mi = 0; mi < 4; ++mi) {                                           \
      const int row_ = wm * 64 + mi * 16 + lr;                                 \
      _Pragma("unroll")                                                        \
      for (int ks = 0; ks < 2; ++ks)                                           \
        a[mi][ks] = *reinterpret_cast<const bf16x8*>(                          \
            &sh[abase + (g) * 8192 + row_ * 64 + ((((ks << 2) + kh) ^ sx) << 3)]); \
    } } while (0)

#define READ_B(dst, n) do {                                                    \
    _Pragma("unroll")                                                          \
    for (int njj = 0; njj < 2; ++njj) {                                        \
      const int row_ = wn * 32 + njj * 16 + lr;                                \
      _Pragma("unroll")                                                        \
      for (int ks = 0; ks < 2; ++ks)                                           \
        dst[njj][ks] = *reinterpret_cast<const bf16x8*>(                       \
            &sh[bbase + (n) * 8192 + row_ * 64 + ((((ks << 2) + kh) ^ sx) << 3)]); \
    } } while (0)

#define MFMA_PH(g, n, bb) do {                                                 \
    __builtin_amdgcn_s_setprio(1);                                             \
    _Pragma("unroll")                                                          \
    for (int mi = 0; mi < 4; ++mi)                                             \
      _Pragma("unroll")                                                        \
      for (int njj = 0; njj < 2; ++njj)                                        \
        _Pragma("unroll")                                                      \
        for (int ks = 0; ks < 2; ++ks)                                         \
          acc[(g) * 4 + mi][(n) * 2 + njj] =                                   \
              __builtin_amdgcn_mfma_f32_16x16x32_bf16(                         \
                  bb[njj][ks], a[mi][ks], acc[(g) * 4 + mi][(n) * 2 + njj],    \
                  0, 0, 0);                                                    \
    __builtin_amdgcn_s_setprio(0); } while (0)

template<int EPI>
__global__ __launch_bounds__(512, 1) void gemm256(
    const short* __restrict__ A, const short* __restrict__ Bw,
    int K, long long sA, long long sB,
    const float* __restrict__ fin,
    float* __restrict__ fout, short* __restrict__ bout,
    short* __restrict__ bout2, short* __restrict__ bout3,
    const short* __restrict__ A2, const short* __restrict__ B2) {
  __shared__ short sh[65536];               // 128 KiB
  const int tid = threadIdx.x;
  const int w = tid >> 6, l = tid & 63;
  const int wm = w >> 2, wn = w & 3;        // 2 M-waves x 4 N-waves
  const int lr = l & 15, kh = l >> 4;
  const int sx = lr & 7;
  int bx = blockIdx.x, by = blockIdx.y;
  const int z = blockIdx.z;
  if constexpr (EPI == 1) {                 // triangular: bx<=by
    int idx = blockIdx.x;
    by = 0;
    while ((by + 1) * (by + 2) / 2 <= idx) ++by;
    bx = idx - by * (by + 1) / 2;
  }
  const int bm = by * 256, bn = bx * 256;
  const short* Ab; const short* Bb;
  if constexpr (EPI == 8) {
    if (z < 8) { Ab = A  + (size_t)z * 262144;       Bb = Bw + (size_t)z * 262144; }
    else       { Ab = A2 + (size_t)(z - 8) * 262144; Bb = B2 + (size_t)(z - 8) * 262144; }
  } else if constexpr (EPI == 1 || EPI == 7) {
    Ab = A + (size_t)z * sA;                 // per-(b,h)
    Bb = Bw + (size_t)(z >> 3) * sB;         // per-batch (shared across heads)
  } else if constexpr (EPI == 6) {
    Ab = z ? A2 : A; Bb = z ? B2 : Bw;
  } else {
    Ab = A + (size_t)z * sA; Bb = Bw + (size_t)z * sB;
  }

  const int kend = (EPI == 2) ? (bm + 256) : K;
  const int NT = kend >> 6;

  f32x4 acc[8][4];
  #pragma unroll
  for (int mf = 0; mf < 8; ++mf)
    #pragma unroll
    for (int nf = 0; nf < 4; ++nf) acc[mf][nf] = (f32x4){0.f, 0.f, 0.f, 0.f};

  // prologue: tile0 all 4 halves, then tile1 {A0, B0, A1}
  STAGEH(0,     Ab, bm,       0);
  STAGEH(8192,  Ab, bm + 128, 0);
  STAGEH(32768, Bb, bn,       0);
  STAGEH(40960, Bb, bn + 128, 0);
  if (NT > 1) {
    STAGEH(16384, Ab, bm,       64);
    STAGEH(49152, Bb, bn,       64);
    STAGEH(24576, Ab, bm + 128, 64);
    asm volatile("s_waitcnt vmcnt(6)" ::: "memory");
  } else {
    asm volatile("s_waitcnt vmcnt(0)" ::: "memory");
  }
  __builtin_amdgcn_s_barrier();

  bf16x8 a[4][2], b0[2][2], b1[2][2];

  for (int t = 0; t < NT; ++t) {
    const int cb = t & 1;
    const int abase = cb * 16384;
    const int bbase = 32768 + cb * 16384;
    const int b2base = 32768 + (cb ^ 1) * 16384;
    const int kc1 = (t + 1) << 6, kc2 = (t + 2) << 6;
    const bool m1 = (t + 1 < NT), m2 = (t + 2 < NT);

    // ---- ph0 ----
    READ_A(0);
    READ_B(b0, 0);
    if (m1) STAGEH(b2base + 8192, Bb, bn + 128, kc1);
    __builtin_amdgcn_s_barrier();
    asm volatile("s_waitcnt lgkmcnt(0)" ::: "memory");
    __builtin_amdgcn_sched_barrier(0);
    MFMA_PH(0, 0, b0);
    __builtin_amdgcn_s_barrier();

    // ---- ph1 ----
    READ_B(b1, 1);
    if (m2) STAGEH(abase, Ab, bm, kc2);
    __builtin_amdgcn_s_barrier();
    asm volatile("s_waitcnt lgkmcnt(0)" ::: "memory");
    __builtin_amdgcn_sched_barrier(0);
    MFMA_PH(0, 1, b1);
    __builtin_amdgcn_s_barrier();

    // ---- ph2 ----
    READ_A(1);
    if (m2) STAGEH(bbase, Bb, bn, kc2);
    __builtin_amdgcn_s_barrier();
    asm volatile("s_waitcnt lgkmcnt(0)" ::: "memory");
    __builtin_amdgcn_sched_barrier(0);
    MFMA_PH(1, 0, b0);
    __builtin_amdgcn_s_barrier();

    // ---- ph3 ----
    if (m2) STAGEH(abase + 8192, Ab, bm + 128, kc2);
    __builtin_amdgcn_s_barrier();
    __builtin_amdgcn_sched_barrier(0);
    MFMA_PH(1, 1, b1);
    if (m1) {
      if (m2) asm volatile("s_waitcnt vmcnt(6)" ::: "memory");
      else    asm volatile("s_waitcnt vmcnt(0)" ::: "memory");
      __builtin_amdgcn_s_barrier();
    }
  }

  // Epilogue. Swapped-operand C layout: lane owns row (lr field) x 4 cols.
  #pragma unroll
  for (int mf = 0; mf < 8; ++mf) {
    const int grow = bm + (mf >> 2) * 128 + wm * 64 + (mf & 3) * 16 + lr;
    #pragma unroll
    for (int nf = 0; nf < 4; ++nf) {
      const int gcol0 = bn + (nf >> 1) * 128 + wn * 32 + (nf & 1) * 16 + kh * 4;
      const float v0 = acc[mf][nf][0], v1 = acc[mf][nf][1];
      const float v2 = acc[mf][nf][2], v3 = acc[mf][nf][3];
      if constexpr (EPI == 0) {
        const int b = grow >> 10, lw = grow & 1023;
        if (bn < 4096) {    // qn [B,H,L,D]
          const int h = gcol0 >> 9, o = gcol0 & 511;
          *reinterpret_cast<short4*>(&bout[(((size_t)(b * 8 + h)) * 1024 + lw) * 512 + o]) =
              make_short4(f2bf(v0), f2bf(v1), f2bf(v2), f2bf(v3));
        } else {            // v^T [B,H,D,L]
          const int n2 = gcol0 - 4096, h = n2 >> 9, o = n2 & 511;
          const size_t base = ((size_t)(b * 8 + h)) * 512;
          bout3[(base + o + 0) * 1024 + lw] = f2bf(v0);
          bout3[(base + o + 1) * 1024 + lw] = f2bf(v1);
          bout3[(base + o + 2) * 1024 + lw] = f2bf(v2);
          bout3[(base + o + 3) * 1024 + lw] = f2bf(v3);
        }
      } else if constexpr (EPI == 1) {
        short4 o;
        o.x = (gcol0 + 0 > grow) ? (short)0 : f2bf(__expf(v0 * SCALE - 8.0f));
        o.y = (gcol0 + 1 > grow) ? (short)0 : f2bf(__expf(v1 * SCALE - 8.0f));
        o.z = (gcol0 + 2 > grow) ? (short)0 : f2bf(__expf(v2 * SCALE - 8.0f));
        o.w = (gcol0 + 3 > grow) ? (short)0 : f2bf(__expf(v3 * SCALE - 8.0f));
        *reinterpret_cast<short4*>(&bout[(size_t)z * 1048576 + (size_t)grow * 1024 + gcol0]) = o;
      } else if constexpr (EPI == 2) {
        const float inv = fin[(size_t)z * 1024 + grow];
        const int b = z >> 3, h = z & 7;
        *reinterpret_cast<short4*>(&bout[((size_t)(b * 1024 + grow)) * 4096 + h * 512 + gcol0]) =
            make_short4(f2bf(v0 * inv), f2bf(v1 * inv), f2bf(v2 * inv), f2bf(v3 * inv));
      } else if constexpr (EPI == 6) {
        const int b = grow >> 10, lw = grow & 1023;
        const int h = gcol0 >> 9, o = gcol0 & 511;
        short* bo = bout + (size_t)z * 16777216;
        *reinterpret_cast<short4*>(&bo[(((size_t)(b * 8 + h)) * 1024 + lw) * 512 + o]) =
            make_short4(f2bf(v0), f2bf(v1), f2bf(v2), f2bf(v3));
      } else if constexpr (EPI == 7) {
        short4 o;
        o.x = f2bf(__expf(v0 * SCALE - 8.0f));
        o.y = f2bf(__expf(v1 * SCALE - 8.0f));
        o.z = f2bf(__expf(v2 * SCALE - 8.0f));
        o.w = f2bf(__expf(v3 * SCALE - 8.0f));
        *reinterpret_cast<short4*>(&bout[(size_t)z * 1048576 + (size_t)grow * 1024 + gcol0]) = o;
      } else if constexpr (EPI == 8) {
        // write C^T: Nh^T[j][i] = N_h[i][j]; strided scalar stores (tiny kernel)
        short* bo = ((z < 8) ? bout : bout2) + (size_t)(z & 7) * 262144;
        bo[(size_t)(gcol0 + 0) * 512 + grow] = f2bf(v0);
        bo[(size_t)(gcol0 + 1) * 512 + grow] = f2bf(v1);
        bo[(size_t)(gcol0 + 2) * 512 + grow] = f2bf(v2);
        bo[(size_t)(gcol0 + 3) * 512 + grow] = f2bf(v3);
      }
    }
  }
}

// ---------------- old 128-tile kernel (N<=2048 shapes) ----------------
// EPI 3: sa -> fout = fin + val   EPI 4: ffn1-gelu   EPI 5: ffn2
template<int EPI, int BN>
__global__ __launch_bounds__(256, 2) void gemm_nt(
    const short* __restrict__ A, const short* __restrict__ Bw,
    int K, const float* __restrict__ fin, const float* __restrict__ fin2,
    float* __restrict__ fout, short* __restrict__ bout) {
  constexpr int NJ = BN / 32;
  __shared__ short As[128 * 32];
  __shared__ short Bs[BN * 32];
  const int tid = threadIdx.x;
  const int w = tid >> 6, l = tid & 63;
  const int wr = w >> 1, wc = w & 1;
  const int lr = l & 15, kh = l >> 4;
  const int bm = blockIdx.y * 128, bn = blockIdx.x * BN;
  const int ar = w * 16 + (l >> 2);
  const int ac = (l & 3) * 8;

  f32x4 acc[4][NJ];
  #pragma unroll
  for (int i = 0; i < 4; ++i)
    #pragma unroll
    for (int j = 0; j < NJ; ++j) acc[i][j] = (f32x4){0.f, 0.f, 0.f, 0.f};

  for (int k0 = 0; k0 < K; k0 += 32) {
    #pragma unroll
    for (int c = 0; c < 2; ++c)
      gload16(A + (size_t)(bm + c * 64 + ar) * K + k0 + ac, &As[c * 2048 + w * 512]);
    #pragma unroll
    for (int c = 0; c < BN / 64; ++c)
      gload16(Bw + (size_t)(bn + c * 64 + ar) * K + k0 + ac, &Bs[c * 2048 + w * 512]);
    __syncthreads();
    bf16x8 af[4], bfr[NJ];
    #pragma unroll
    for (int i = 0; i < 4; ++i)
      af[i] = *reinterpret_cast<const bf16x8*>(&As[(wr * 64 + i * 16 + lr) * 32 + kh * 8]);
    #pragma unroll
    for (int j = 0; j < NJ; ++j)
      bfr[j] = *reinterpret_cast<const bf16x8*>(&Bs[(wc * (BN / 2) + j * 16 + lr) * 32 + kh * 8]);
    #pragma unroll
    for (int i = 0; i < 4; ++i)
      #pragma unroll
      for (int j = 0; j < NJ; ++j)
        acc[i][j] = __builtin_amdgcn_mfma_f32_16x16x32_bf16(bfr[j], af[i], acc[i][j], 0, 0, 0);
    __syncthreads();
  }

  #pragma unroll
  for (int i = 0; i < 4; ++i) {
    const int grow = bm + wr * 64 + i * 16 + lr;
    #pragma unroll
    for (int j = 0; j < NJ; ++j) {
      const int gcol0 = bn + wc * (BN / 2) + j * 16 + kh * 4;
      const float v0 = acc[i][j][0], v1 = acc[i][j][1];
      const float v2 = acc[i][j][2], v3 = acc[i][j][3];
      if constexpr (EPI == 3) {
        const size_t idx = (size_t)grow * 512 + gcol0;
        const float4 t4 = *reinterpret_cast<const float4*>(&fin[idx]);
        float4 f; f.x = t4.x + v0; f.y = t4.y + v1; f.z = t4.z + v2; f.w = t4.w + v3;
        *reinterpret_cast<float4*>(&fout[idx]) = f;
      } else if constexpr (EPI == 4) {
        const float4 b4 = *reinterpret_cast<const float4*>(&fin[gcol0]);
        const float x0 = v0 + b4.x, x1 = v1 + b4.y, x2 = v2 + b4.z, x3 = v3 + b4.w;
        const float g0 = 0.5f * x0 * (1.0f + erff(x0 * 0.70710678118654752f));
        const float g1 = 0.5f * x1 * (1.0f + erff(x1 * 0.70710678118654752f));
        const float g2 = 0.5f * x2 * (1.0f + erff(x2 * 0.70710678118654752f));
        const float g3 = 0.5f * x3 * (1.0f + erff(x3 * 0.70710678118654752f));
        *reinterpret_cast<short4*>(&bout[(size_t)grow * 2048 + gcol0]) =
            make_short4(f2bf(g0), f2bf(g1), f2bf(g2), f2bf(g3));
      } else if constexpr (EPI == 5) {
        const size_t idx = (size_t)grow * 512 + gcol0;
        const float4 a4 = *reinterpret_cast<const float4*>(&fin2[idx]);
        const float4 b4 = *reinterpret_cast<const float4*>(&fin[gcol0]);
        float4 f;
        f.x = a4.x + v0 + b4.x; f.y = a4.y + v1 + b4.y;
        f.z = a4.z + v2 + b4.z; f.w = a4.w + v3 + b4.w;
        *reinterpret_cast<float4*>(&fout[idx]) = f;
        *reinterpret_cast<short4*>(&bout[idx]) =
            make_short4(f2bf(f.x), f2bf(f.y), f2bf(f.z), f2bf(f.w));
      }
    }
  }
}

// ---------------------------------------------------------------------------
extern "C" void kernel_launch(void* const* d_in, const int* in_sizes, int n_in,
                              void* d_out, int out_size, void* d_ws, size_t ws_size,
                              hipStream_t stream) {
  const float* tokens = (const float*)d_in[0];
  const float* ln1g = (const float*)d_in[3];
  const float* ln1b = (const float*)d_in[4];
  const float* ln2g = (const float*)d_in[5];
  const float* ln2b = (const float*)d_in[6];
  const float* wq = (const float*)d_in[7];
  const float* wk = (const float*)d_in[8];
  const float* wv = (const float*)d_in[9];
  const float* wo = (const float*)d_in[10];
  const float* w1 = (const float*)d_in[11];
  const float* b1 = (const float*)d_in[12];
  const float* w2 = (const float*)d_in[13];
  const float* b2 = (const float*)d_in[14];
  const float* cwk = (const float*)d_in[15];
  const float* cwq = (const float*)d_in[17];

  float* out_t = (float*)d_out;
  float* out_self = out_t + 2097152;
  float* out_cross = out_self + 33554432;

  char* ws = (char*)d_ws;
  size_t off = 0;
  auto alloc = [&](size_t bytes) -> void* {
    void* p = ws + off; off = (off + bytes + 255) & ~(size_t)255; return p;
  };
  short* xb   = (short*)alloc(2097152ull * 2);   // LN1(tokens) bf16
  short* tokb = (short*)alloc(2097152ull * 2);   // tokens bf16
  float* tf   = (float*)alloc(2097152ull * 4);   // t after attention, f32
  short* tb   = (short*)alloc(2097152ull * 2);   // final t bf16
  short* yb   = (short*)alloc(2097152ull * 2);   // LN2(t) bf16
  short* h1b  = (short*)alloc(8388608ull * 2);   // gelu hidden
  short* qb   = (short*)alloc(16777216ull * 2);  // qn [B,H,L,D]; later tM
  short* vtb  = (short*)alloc(16777216ull * 2);  // v^T [B,H,D,L]
  short* Eb   = (short*)alloc(33554432ull * 2);  // exp(logit-8) bf16
  short* comb = (short*)alloc(16777216ull * 2);  // ctx [B,L,H*D]
  short* Wstk = (short*)alloc(4194304ull * 2);   // [NhT(4096); wv(4096)] x 512
  short* Mstk = (short*)alloc(2097152ull * 2);   // MhT [4096,512]
  short* wop  = (short*)alloc(2097152ull * 2);
  short* w1b  = (short*)alloc(1048576ull * 2);
  short* w2b  = (short*)alloc(1048576ull * 2);
  short* wqT  = (short*)alloc(2097152ull * 2);
  short* wkT  = (short*)alloc(2097152ull * 2);
  short* cwqT = (short*)alloc(2097152ull * 2);
  short* cwkT = (short*)alloc(2097152ull * 2);
  float* inv_s = (float*)alloc(32768ull * 4);

  // weight prep
  transpose_w<<<dim3(16, 16, 32), 256, 0, stream>>>(wq, wk, cwq, cwk,
                                                    wqT, wkT, cwqT, cwkT);
  cvt_multi<<<4096, 256, 0, stream>>>(wv, w1, w2, Wstk + 2097152, w1b, w2b);
  permute_wo<<<8192, 256, 0, stream>>>(wo, wop);
  // NhT (z<8) -> Wstk[0:4096], MhT (z>=8) -> Mstk
  gemm256<8><<<dim3(2, 2, 16), 512, 0, stream>>>(wqT, wkT, 512, 0, 0,
      nullptr, nullptr, Wstk, Mstk, nullptr, cwqT, cwkT);
  // LN1 (also emits tokens bf16)
  ln_rows<<<4096, 256, 0, stream>>>(tokens, ln1g, ln1b, xb, tokb);
  // qn + v: [4096,512] x [8192,512]^T
  gemm256<0><<<dim3(32, 16, 1), 512, 0, stream>>>(xb, Wstk, 512, 0, 0,
      nullptr, nullptr, qb, nullptr, vtb, nullptr, nullptr);
  // self E: qn . x^T, triangular 256-tiles x 32 heads (B per-batch stride)
  gemm256<1><<<dim3(10, 1, 32), 512, 0, stream>>>(qb, xb, 512, 524288, 524288,
      nullptr, nullptr, Eb, nullptr, nullptr, nullptr, nullptr);
  rownorm<1><<<8192, 256, 0, stream>>>(Eb, out_self, inv_s);
  // PV on raw E, scale by inv in epilogue; K truncated per row-tile
  gemm256<2><<<dim3(2, 4, 32), 512, 0, stream>>>(Eb, vtb, 1024, 1048576, 524288,
      inv_s, nullptr, comb, nullptr, nullptr, nullptr, nullptr);
  // sa + residual
  gemm_nt<3, 64><<<dim3(8, 32, 1), 256, 0, stream>>>(comb, wop, 4096,
      tokens, nullptr, tf, nullptr);
  ln_rows<<<4096, 256, 0, stream>>>(tf, ln2g, ln2b, yb, nullptr);
  // ffn1 + gelu (128-tile: 512 blocks, full occupancy)
  gemm_nt<4, 128><<<dim3(16, 32, 1), 256, 0, stream>>>(yb, w1b, 512,
      b1, nullptr, nullptr, h1b);
  // ffn2 + residuals
  gemm_nt<5, 64><<<dim3(8, 32, 1), 256, 0, stream>>>(h1b, w2b, 2048,
      b2, tf, out_t, tb);
  // tM = t * MhT  (reuse qb; qn dead)
  gemm256<6><<<dim3(16, 16, 1), 512, 0, stream>>>(tb, Mstk, 512, 0, 0,
      nullptr, nullptr, qb, nullptr, nullptr, tb, Mstk);
  // cross E: tM . tokens^T (B per-batch stride)
  gemm256<7><<<dim3(4, 4, 32), 512, 0, stream>>>(qb, tokb, 512, 524288, 524288,
      nullptr, nullptr, Eb, nullptr, nullptr, nullptr, nullptr);
  rownorm<0><<<8192, 256, 0, stream>>>(Eb, out_cross, nullptr);
}